// Round 1
// baseline (157.517 us; speedup 1.0000x reference)
//
#include <hip/hip_runtime.h>
#include <hip/hip_bf16.h>
#include <math.h>

typedef _Float16 f16_t;
typedef _Float16 f16x8 __attribute__((ext_vector_type(8)));
typedef float f32x16 __attribute__((ext_vector_type(16)));

#define NROWS 32768
#define DD 32
#define TILE_M 64
#define SIG_OFF (NROWS * 64)

// ws layout (elements of f16)
#define W3T_OFF  131072            // after W2T: 32*64*64
#define RW1T_OFF 393216            // after W3T: +32*128*64
#define RW2T_OFF 401408            // after rW1T: +64*128
#define RW3T_OFF 405504            // after rW2T: +64*64
#define WS_ELEMS 413696            // +128*64

// Transpose + fp32->fp16 convert all GEMM weights into workspace.
// Layouts: W2T[d][n][k]=W2[d][k][n]; W3T[d][n][k]=W3[d][k][n];
//          rW1T[n][k]=rW1[k][n]; rW2T[n][k]=rW2[k][n]; rW3T[n][k]=rW3[k][n]
__global__ void convert_weights(const float* __restrict__ W2,
                                const float* __restrict__ W3,
                                const float* __restrict__ rW1,
                                const float* __restrict__ rW2,
                                const float* __restrict__ rW3,
                                f16_t* __restrict__ ws) {
  for (int i = blockIdx.x * blockDim.x + threadIdx.x; i < WS_ELEMS;
       i += gridDim.x * blockDim.x) {
    float v;
    if (i < W3T_OFF) {
      int d = i >> 12, rem = i & 4095, n = rem >> 6, k = rem & 63;
      v = W2[(d * 64 + k) * 64 + n];
    } else if (i < RW1T_OFF) {
      int j = i - W3T_OFF;
      int d = j >> 13, rem = j & 8191, n = rem >> 6, k = rem & 63;
      v = W3[(d * 64 + k) * 128 + n];
    } else if (i < RW2T_OFF) {
      int j = i - RW1T_OFF, n = j >> 7, k = j & 127;
      v = rW1[k * 64 + n];
    } else if (i < RW3T_OFF) {
      int j = i - RW2T_OFF, n = j >> 6, k = j & 63;
      v = rW2[k * 64 + n];
    } else {
      int j = i - RW3T_OFF, n = j >> 6, k = j & 63;
      v = rW3[k * 128 + n];
    }
    ws[i] = (f16_t)v;
  }
}

__device__ __forceinline__ float softplus_f(float v) {
  // jax.nn.softplus = logaddexp(v, 0)
  return fmaxf(v, 0.f) + log1pf(expf(-fabsf(v)));
}

// Block = 256 threads (4 waves, 2x2 wave grid) owns TILE_M=64 rows.
// Wave (mw,nw): rows [mw*32,+32), cols: GEMM1 [nw*32,+32); GEMM2/R3 [nw*64,+64).
// MFMA 32x32x16 fragment maps (gfx950, verified C/D m74/m101):
//   A: row=lane&31, k=(lane>>5)*8+j (8 contiguous f16)
//   B: col=lane&31, k=(lane>>5)*8+j
//   C/D: col=lane&31, row=(reg&3)+8*(reg>>2)+4*(lane>>5)
__launch_bounds__(256, 2)
__global__ void indexnet_main(const float* __restrict__ x,
                              const int* __restrict__ mask,
                              const float* __restrict__ W1,
                              const float* __restrict__ b1,
                              const float* __restrict__ b2,
                              const float* __restrict__ b3,
                              const float* __restrict__ rb1,
                              const float* __restrict__ rb2,
                              const float* __restrict__ rb3,
                              const f16_t* __restrict__ ws,
                              float* __restrict__ out) {
  __shared__ float x_lds[TILE_M][33];          // +1 pad: conflict-free column reads
  __shared__ unsigned int maskw_lds[TILE_M];
  __shared__ f16_t h1_lds[TILE_M][72];         // 144B rows (16B aligned), reused as r1
  __shared__ f16_t h2_lds[TILE_M][72];         // reused as r2
  __shared__ f16_t pool_lds[TILE_M][136];      // 272B rows

  const int tid = threadIdx.x;
  const int lane = tid & 63;
  const int wid = tid >> 6;
  const int mw = wid >> 1;
  const int nw = wid & 1;
  const int l31 = lane & 31;
  const int lh = lane >> 5;
  const int row0 = blockIdx.x * TILE_M;

  // ---- stage x tile (coalesced float4 loads, padded LDS writes) ----
  {
    const float4* src = reinterpret_cast<const float4*>(x + (size_t)row0 * DD);
    float4 a = src[tid * 2];
    float4 b = src[tid * 2 + 1];
    int r = tid >> 2;
    int c = (tid & 3) * 8;
    x_lds[r][c + 0] = a.x; x_lds[r][c + 1] = a.y;
    x_lds[r][c + 2] = a.z; x_lds[r][c + 3] = a.w;
    x_lds[r][c + 4] = b.x; x_lds[r][c + 5] = b.y;
    x_lds[r][c + 6] = b.z; x_lds[r][c + 7] = b.w;
  }
  // ---- pack mask rows into 32-bit words (bit d = mask[r][d]) ----
  if (tid < TILE_M) {
    const int* mrow = mask + (size_t)(row0 + tid) * DD;
    unsigned int w = 0;
    #pragma unroll
    for (int d = 0; d < DD; ++d) w |= (mrow[d] ? 1u : 0u) << d;
    maskw_lds[tid] = w;
  }
  __syncthreads();

  // per-lane mask words for this lane's 16 C/D rows (kept in VGPRs for whole d-loop)
  unsigned int mword[16];
  #pragma unroll
  for (int reg = 0; reg < 16; ++reg) {
    int rl = (reg & 3) + 8 * (reg >> 2) + 4 * lh;
    mword[reg] = maskw_lds[mw * 32 + rl];
  }

  f32x16 pool0 = {}, pool1 = {};   // pooled[rows][nw*64 + {l31, 32+l31}], fp32

  for (int d = 0; d < DD; ++d) {
    // ---- h1 = relu(x[:,d]*W1[d] + b1[d]) -> f16 LDS (fp32 math) ----
    {
      int r = tid >> 2;
      int h0 = (tid & 3) * 16;
      float xv = x_lds[r][d];
      f16x8 v0, v1;
      #pragma unroll
      for (int j = 0; j < 8; ++j) {
        v0[j] = (f16_t)fmaxf(xv * W1[d * 64 + h0 + j] + b1[d * 64 + h0 + j], 0.f);
        v1[j] = (f16_t)fmaxf(xv * W1[d * 64 + h0 + 8 + j] + b1[d * 64 + h0 + 8 + j], 0.f);
      }
      *reinterpret_cast<f16x8*>(&h1_lds[r][h0]) = v0;
      *reinterpret_cast<f16x8*>(&h1_lds[r][h0 + 8]) = v1;
    }
    __syncthreads();  // (A) h1 ready; prev-iter h2 reads also complete before this

    // ---- GEMM1: h2 = relu(h1 @ W2[d] + b2[d]), K=64 ----
    f32x16 acc = {};
    const f16_t* w2t = ws + (size_t)d * 4096;
    #pragma unroll
    for (int ks = 0; ks < 4; ++ks) {
      f16x8 a = *reinterpret_cast<const f16x8*>(&h1_lds[mw * 32 + l31][ks * 16 + lh * 8]);
      f16x8 b = *reinterpret_cast<const f16x8*>(w2t + (nw * 32 + l31) * 64 + ks * 16 + lh * 8);
      acc = __builtin_amdgcn_mfma_f32_32x32x16_f16(a, b, acc, 0, 0, 0);
    }
    float b2v = b2[d * 64 + nw * 32 + l31];
    #pragma unroll
    for (int reg = 0; reg < 16; ++reg) {
      int rl = (reg & 3) + 8 * (reg >> 2) + 4 * lh;
      h2_lds[mw * 32 + rl][nw * 32 + l31] = (f16_t)fmaxf(acc[reg] + b2v, 0.f);
    }
    __syncthreads();  // (B) h2 ready; also fences h1 reads before next-iter h1 write

    // ---- GEMM2: o = h2 @ W3[d], masked accumulate into pooled ----
    f32x16 acc0 = {}, acc1 = {};
    const f16_t* w3t = ws + W3T_OFF + (size_t)d * 8192;
    #pragma unroll
    for (int ks = 0; ks < 4; ++ks) {
      f16x8 a = *reinterpret_cast<const f16x8*>(&h2_lds[mw * 32 + l31][ks * 16 + lh * 8]);
      f16x8 bb0 = *reinterpret_cast<const f16x8*>(w3t + (nw * 64 + l31) * 64 + ks * 16 + lh * 8);
      f16x8 bb1 = *reinterpret_cast<const f16x8*>(w3t + (nw * 64 + 32 + l31) * 64 + ks * 16 + lh * 8);
      acc0 = __builtin_amdgcn_mfma_f32_32x32x16_f16(a, bb0, acc0, 0, 0, 0);
      acc1 = __builtin_amdgcn_mfma_f32_32x32x16_f16(a, bb1, acc1, 0, 0, 0);
    }
    float b3v0 = b3[d * 128 + nw * 64 + l31];
    float b3v1 = b3[d * 128 + nw * 64 + 32 + l31];
    #pragma unroll
    for (int reg = 0; reg < 16; ++reg) {
      bool m = (mword[reg] >> d) & 1u;
      pool0[reg] += m ? (acc0[reg] + b3v0) : 0.f;
      pool1[reg] += m ? (acc1[reg] + b3v1) : 0.f;
    }
    // no barrier needed here: next h1-write targets a different buffer and
    // this iteration's h1 reads were fenced by barrier (B).
  }

  // ---- pooled -> f16 LDS for readout GEMMs ----
  #pragma unroll
  for (int reg = 0; reg < 16; ++reg) {
    int rl = (reg & 3) + 8 * (reg >> 2) + 4 * lh;
    pool_lds[mw * 32 + rl][nw * 64 + l31]      = (f16_t)pool0[reg];
    pool_lds[mw * 32 + rl][nw * 64 + 32 + l31] = (f16_t)pool1[reg];
  }
  __syncthreads();

  // ---- R1 = relu(pooled @ rW1 + rb1), K=128 N=64 ----
  {
    f32x16 acc = {};
    const f16_t* rw1t = ws + RW1T_OFF;
    #pragma unroll
    for (int ks = 0; ks < 8; ++ks) {
      f16x8 a = *reinterpret_cast<const f16x8*>(&pool_lds[mw * 32 + l31][ks * 16 + lh * 8]);
      f16x8 b = *reinterpret_cast<const f16x8*>(rw1t + (nw * 32 + l31) * 128 + ks * 16 + lh * 8);
      acc = __builtin_amdgcn_mfma_f32_32x32x16_f16(a, b, acc, 0, 0, 0);
    }
    float bv = rb1[nw * 32 + l31];
    #pragma unroll
    for (int reg = 0; reg < 16; ++reg) {
      int rl = (reg & 3) + 8 * (reg >> 2) + 4 * lh;
      h1_lds[mw * 32 + rl][nw * 32 + l31] = (f16_t)fmaxf(acc[reg] + bv, 0.f);
    }
  }
  __syncthreads();

  // ---- R2 = relu(r1 @ rW2 + rb2), K=64 N=64 ----
  {
    f32x16 acc = {};
    const f16_t* rw2t = ws + RW2T_OFF;
    #pragma unroll
    for (int ks = 0; ks < 4; ++ks) {
      f16x8 a = *reinterpret_cast<const f16x8*>(&h1_lds[mw * 32 + l31][ks * 16 + lh * 8]);
      f16x8 b = *reinterpret_cast<const f16x8*>(rw2t + (nw * 32 + l31) * 64 + ks * 16 + lh * 8);
      acc = __builtin_amdgcn_mfma_f32_32x32x16_f16(a, b, acc, 0, 0, 0);
    }
    float bv = rb2[nw * 32 + l31];
    #pragma unroll
    for (int reg = 0; reg < 16; ++reg) {
      int rl = (reg & 3) + 8 * (reg >> 2) + 4 * lh;
      h2_lds[mw * 32 + rl][nw * 32 + l31] = (f16_t)fmaxf(acc[reg] + bv, 0.f);
    }
  }
  __syncthreads();

  // ---- R3 = r2 @ rW3 + rb3, K=64 N=128 -> mu | softplus(sigma) ----
  {
    f32x16 acc0 = {}, acc1 = {};
    const f16_t* rw3t = ws + RW3T_OFF;
    #pragma unroll
    for (int ks = 0; ks < 4; ++ks) {
      f16x8 a = *reinterpret_cast<const f16x8*>(&h2_lds[mw * 32 + l31][ks * 16 + lh * 8]);
      f16x8 bb0 = *reinterpret_cast<const f16x8*>(rw3t + (nw * 64 + l31) * 64 + ks * 16 + lh * 8);
      f16x8 bb1 = *reinterpret_cast<const f16x8*>(rw3t + (nw * 64 + 32 + l31) * 64 + ks * 16 + lh * 8);
      acc0 = __builtin_amdgcn_mfma_f32_32x32x16_f16(a, bb0, acc0, 0, 0, 0);
      acc1 = __builtin_amdgcn_mfma_f32_32x32x16_f16(a, bb1, acc1, 0, 0, 0);
    }
    float bv0 = rb3[nw * 64 + l31];
    float bv1 = rb3[nw * 64 + 32 + l31];
    #pragma unroll
    for (int reg = 0; reg < 16; ++reg) {
      int rl = (reg & 3) + 8 * (reg >> 2) + 4 * lh;
      size_t grow = (size_t)(row0 + mw * 32 + rl);
      float v0 = acc0[reg] + bv0;
      float v1 = acc1[reg] + bv1;
      if (nw == 0) {      // cols 0..63 -> mu
        out[grow * 64 + l31]      = v0;
        out[grow * 64 + 32 + l31] = v1;
      } else {            // cols 64..127 -> sigma = softplus
        out[SIG_OFF + grow * 64 + l31]      = softplus_f(v0);
        out[SIG_OFF + grow * 64 + 32 + l31] = softplus_f(v1);
      }
    }
  }
}

extern "C" void kernel_launch(void* const* d_in, const int* in_sizes, int n_in,
                              void* d_out, int out_size, void* d_ws, size_t ws_size,
                              hipStream_t stream) {
  const float* x    = (const float*)d_in[0];
  const int*   mask = (const int*)d_in[1];
  const float* W1   = (const float*)d_in[2];
  const float* b1   = (const float*)d_in[3];
  const float* W2   = (const float*)d_in[4];
  const float* b2   = (const float*)d_in[5];
  const float* W3   = (const float*)d_in[6];
  const float* b3   = (const float*)d_in[7];
  const float* rW1  = (const float*)d_in[8];
  const float* rb1  = (const float*)d_in[9];
  const float* rW2  = (const float*)d_in[10];
  const float* rb2  = (const float*)d_in[11];
  const float* rW3  = (const float*)d_in[12];
  const float* rb3  = (const float*)d_in[13];
  float* out = (float*)d_out;
  f16_t* ws = (f16_t*)d_ws;

  convert_weights<<<256, 256, 0, stream>>>(W2, W3, rW1, rW2, rW3, ws);
  indexnet_main<<<NROWS / TILE_M, 256, 0, stream>>>(
      x, mask, W1, b1, b2, b3, rb1, rb2, rb3, ws, out);
}

// Round 3
// 113.410 us; speedup vs baseline: 1.3889x; 1.3889x over previous
//
#include <hip/hip_runtime.h>
#include <hip/hip_bf16.h>
#include <math.h>

typedef _Float16 f16_t;
typedef _Float16 f16x8 __attribute__((ext_vector_type(8)));
typedef float f32x16 __attribute__((ext_vector_type(16)));
typedef unsigned int uintx4 __attribute__((ext_vector_type(4)));
typedef unsigned int uintx2 __attribute__((ext_vector_type(2)));

#define NROWS 32768
#define DD 32
#define SIG_OFF (NROWS * 64)

// ws layout (f16 elements)
#define W2T_OFF  0                 // [32 d][64 n][64 k]   (W2T[d][n][k] = W2[d][k][n])
#define W3T_OFF  131072            // [32 d][128 n][64 k]
#define RW1T_OFF 393216            // [64 n][128 k]
#define RW2T_OFF 401408            // [64 n][64 k]
#define RW3T_OFF 405504            // [128 n][64 k]
#define W1F_OFF  413696            // [32 d][64]  f16 copy of W1
#define B1F_OFF  415744            // [32 d][64]  f16 copy of b1
#define B3T_OFF  417792            // [128 n][32 d]  (b3T[n][d] = b3[d][n])
#define WS_ELEMS 421888

__global__ void convert_weights(const float* __restrict__ W1,
                                const float* __restrict__ b1,
                                const float* __restrict__ W2,
                                const float* __restrict__ W3,
                                const float* __restrict__ b3,
                                const float* __restrict__ rW1,
                                const float* __restrict__ rW2,
                                const float* __restrict__ rW3,
                                f16_t* __restrict__ ws) {
  for (int i = blockIdx.x * blockDim.x + threadIdx.x; i < WS_ELEMS;
       i += gridDim.x * blockDim.x) {
    float v;
    if (i < W3T_OFF) {
      int d = i >> 12, rem = i & 4095, n = rem >> 6, k = rem & 63;
      v = W2[(d * 64 + k) * 64 + n];
    } else if (i < RW1T_OFF) {
      int j = i - W3T_OFF;
      int d = j >> 13, rem = j & 8191, n = rem >> 6, k = rem & 63;
      v = W3[(d * 64 + k) * 128 + n];
    } else if (i < RW2T_OFF) {
      int j = i - RW1T_OFF, n = j >> 7, k = j & 127;
      v = rW1[k * 64 + n];
    } else if (i < RW3T_OFF) {
      int j = i - RW2T_OFF, n = j >> 6, k = j & 63;
      v = rW2[k * 64 + n];
    } else if (i < W1F_OFF) {
      int j = i - RW3T_OFF, n = j >> 6, k = j & 63;
      v = rW3[k * 128 + n];
    } else if (i < B1F_OFF) {
      v = W1[i - W1F_OFF];
    } else if (i < B3T_OFF) {
      v = b1[i - B1F_OFF];
    } else {
      int j = i - B3T_OFF, n = j >> 5, d = j & 31;
      v = b3[d * 128 + n];
    }
    ws[i] = (f16_t)v;
  }
}

// Transpose a swapped-GEMM C tile (lane = data-row l31, regs = 16 n-values:
// n = (reg&3)+8*(reg>>2)+4*lh) into two B fragments (lane supplies
// n = 16*kk + 8*lh + j, j=0..7 contiguous) via a PER-WAVE private LDS
// round-trip. `row` = this wave's 18-u32 scratch row for l31; both lane
// halves (l31, l31+32) share it. Col c holds the f16 pair {n=2c, n=2c+1}.
// Write cols: 4a+2lh+{0,1}; read cols: 8kk+4lh+{0..3}. Within-wave
// ds_write->ds_read ordering is a compiler-visible LDS dependence (lgkmcnt
// inserted automatically) -- no barrier needed.
__device__ __forceinline__ void xpose2(const f32x16& c, unsigned* row, int lh,
                                       f16x8& o0, f16x8& o1) {
  #pragma unroll
  for (int a = 0; a < 4; ++a) {
    uintx2 w;
    w.x = __builtin_bit_cast(unsigned, __builtin_amdgcn_cvt_pkrtz(c[4 * a + 0], c[4 * a + 1]));
    w.y = __builtin_bit_cast(unsigned, __builtin_amdgcn_cvt_pkrtz(c[4 * a + 2], c[4 * a + 3]));
    *reinterpret_cast<uintx2*>(row + 4 * a + 2 * lh) = w;
  }
  uintx2 ra = *reinterpret_cast<const uintx2*>(row + 4 * lh);
  uintx2 rb = *reinterpret_cast<const uintx2*>(row + 4 * lh + 2);
  uintx2 rc = *reinterpret_cast<const uintx2*>(row + 8 + 4 * lh);
  uintx2 rd = *reinterpret_cast<const uintx2*>(row + 8 + 4 * lh + 2);
  uintx4 w0 = {ra.x, ra.y, rb.x, rb.y};
  uintx4 w1 = {rc.x, rc.y, rd.x, rd.y};
  o0 = __builtin_bit_cast(f16x8, w0);
  o1 = __builtin_bit_cast(f16x8, w1);
}

// Block = 256 thr = 4 waves = 2 pairs. Pair p owns rows blk*64+p*32+(lane&31).
// Wave parity q: d-range [q*16, q*16+16). All layer GEMMs are computed
// swapped (C' = W^T x act^T) so activations stay lane-local; transposes via
// per-wave LDS round-trip (xpose2). Pool accumulates inside the GEMM2 MFMA
// accumulator across d (mask folded into h2). Barriers: 2 total.
__launch_bounds__(256, 2)
__global__ void indexnet_main(const float* __restrict__ x,
                              const int* __restrict__ mask,
                              const float* __restrict__ b2,
                              const float* __restrict__ rb1,
                              const float* __restrict__ rb2,
                              const float* __restrict__ rb3,
                              const f16_t* __restrict__ ws,
                              float* __restrict__ out) {
  __shared__ float x_lds[64][33];
  __shared__ float b2_lds[32][64];
  __shared__ float rb_lds[256];                        // rb1 | rb2 | rb3
  __shared__ float pool_lds[2][2][32][68];             // [pair][lh][l31][64+pad]
  __shared__ __align__(16) unsigned xp_lds[4][2][32][18];  // per-wave xpose scratch

  const int tid = threadIdx.x;
  const int lane = tid & 63;
  const int wid = tid >> 6;
  const int p = wid >> 1;          // pair (row group)
  const int q = wid & 1;           // d-range half
  const int l31 = lane & 31;
  const int lh = lane >> 5;
  const int row0 = blockIdx.x * 64;

  unsigned* xrow0 = &xp_lds[wid][0][l31][0];
  unsigned* xrow1 = &xp_lds[wid][1][l31][0];

  // ---- stage x tile [64][32] ----
  {
    const float4* src = reinterpret_cast<const float4*>(x + (size_t)row0 * DD);
    float4 a = src[tid * 2];
    float4 b = src[tid * 2 + 1];
    int r = tid >> 2, c = (tid & 3) * 8;
    x_lds[r][c + 0] = a.x; x_lds[r][c + 1] = a.y; x_lds[r][c + 2] = a.z; x_lds[r][c + 3] = a.w;
    x_lds[r][c + 4] = b.x; x_lds[r][c + 5] = b.y; x_lds[r][c + 6] = b.z; x_lds[r][c + 7] = b.w;
  }
  // ---- stage b2 [32][64] (flat copy) ----
  {
    float4* dst = reinterpret_cast<float4*>(&b2_lds[0][0]);
    const float4* src = reinterpret_cast<const float4*>(b2);
    dst[tid * 2] = src[tid * 2];
    dst[tid * 2 + 1] = src[tid * 2 + 1];
  }
  // ---- stage readout biases ----
  if (tid < 64)       rb_lds[tid] = rb1[tid];
  else if (tid < 128) rb_lds[tid] = rb2[tid - 64];
  else                rb_lds[tid] = rb3[tid - 128];

  // ---- per-lane mask word for own row ----
  unsigned mword = 0;
  {
    const int4* mrow = reinterpret_cast<const int4*>(mask + (size_t)(row0 + p * 32 + l31) * DD);
    #pragma unroll
    for (int c4 = 0; c4 < 8; ++c4) {
      int4 m = mrow[c4];
      mword |= (m.x != 0 ? 1u : 0u) << (4 * c4);
      mword |= (m.y != 0 ? 1u : 0u) << (4 * c4 + 1);
      mword |= (m.z != 0 ? 1u : 0u) << (4 * c4 + 2);
      mword |= (m.w != 0 ? 1u : 0u) << (4 * c4 + 3);
    }
  }
  __syncthreads();   // barrier #1

  f32x16 acc[4] = {};     // pooled^T accumulator: tile t -> n = 32t + rl, lane = row
  const int dbase = q * 16;

  for (int dd = 0; dd < 16; ++dd) {
    const int d = dbase + dd;
    const f16_t* w2t = ws + W2T_OFF + d * 4096 + l31 * 64 + lh * 8;
    const f16_t* w3t = ws + W3T_OFF + d * 8192 + l31 * 64 + lh * 8;
    f16x8 wf2[2][4];
    #pragma unroll
    for (int t = 0; t < 2; ++t)
      #pragma unroll
      for (int ks = 0; ks < 4; ++ks)
        wf2[t][ks] = *reinterpret_cast<const f16x8*>(w2t + t * 2048 + ks * 16);

    // ---- h1 fragments in packed f16: h1[l31][16ks+8lh+j] ----
    float xv = x_lds[p * 32 + l31][d];
    f16_t xh = (f16_t)xv;
    f16x8 xv8 = {xh, xh, xh, xh, xh, xh, xh, xh};
    f16x8 h1f[4];
    const f16_t* w1p = ws + W1F_OFF + d * 64 + lh * 8;
    const f16_t* b1p = ws + B1F_OFF + d * 64 + lh * 8;
    #pragma unroll
    for (int ks = 0; ks < 4; ++ks) {
      f16x8 w1 = *reinterpret_cast<const f16x8*>(w1p + ks * 16);
      f16x8 bb = *reinterpret_cast<const f16x8*>(b1p + ks * 16);
      f16x8 h = xv8 * w1 + bb;
      h1f[ks] = __builtin_elementwise_max(h, (f16x8)(f16_t)0);
    }

    // ---- GEMM1 (swapped): h2^T = W2T x h1^T, acc init = b2 ----
    f32x16 hacc[2];
    #pragma unroll
    for (int t = 0; t < 2; ++t)
      #pragma unroll
      for (int a = 0; a < 4; ++a) {
        float4 bv = *reinterpret_cast<const float4*>(&b2_lds[d][t * 32 + a * 8 + lh * 4]);
        hacc[t][4 * a + 0] = bv.x; hacc[t][4 * a + 1] = bv.y;
        hacc[t][4 * a + 2] = bv.z; hacc[t][4 * a + 3] = bv.w;
      }
    #pragma unroll
    for (int ks = 0; ks < 4; ++ks) {
      hacc[0] = __builtin_amdgcn_mfma_f32_32x32x16_f16(wf2[0][ks], h1f[ks], hacc[0], 0, 0, 0);
      hacc[1] = __builtin_amdgcn_mfma_f32_32x32x16_f16(wf2[1][ks], h1f[ks], hacc[1], 0, 0, 0);
    }
    // relu + mask (lane = data row for C cols)
    const bool mb = (mword >> d) & 1u;
    #pragma unroll
    for (int t = 0; t < 2; ++t)
      #pragma unroll
      for (int r = 0; r < 16; ++r) {
        float v = fmaxf(hacc[t][r], 0.f);
        hacc[t][r] = mb ? v : 0.f;
      }
    // LDS-based in-wave transpose -> GEMM2 B fragments
    f16x8 pf[4];
    xpose2(hacc[0], xrow0, lh, pf[0], pf[1]);
    xpose2(hacc[1], xrow1, lh, pf[2], pf[3]);

    // ---- GEMM2 (swapped): pooled^T += W3T x (m*h2)^T  (acc across d) ----
    #pragma unroll
    for (int t = 0; t < 4; ++t)
      #pragma unroll
      for (int ks = 0; ks < 4; ++ks) {
        f16x8 wf = *reinterpret_cast<const f16x8*>(w3t + t * 2048 + ks * 16);
        acc[t] = __builtin_amdgcn_mfma_f32_32x32x16_f16(wf, pf[ks], acc[t], 0, 0, 0);
      }
  }

  // ---- pool combine across the wave pair ----
  if (q == 1) {
    #pragma unroll
    for (int t = 0; t < 4; ++t)
      #pragma unroll
      for (int a = 0; a < 4; ++a) {
        float4 f = {acc[t][4 * a], acc[t][4 * a + 1], acc[t][4 * a + 2], acc[t][4 * a + 3]};
        *reinterpret_cast<float4*>(&pool_lds[p][lh][l31][(t * 4 + a) * 4]) = f;
      }
  }
  __syncthreads();   // barrier #2
  if (q == 1) return;

  #pragma unroll
  for (int t = 0; t < 4; ++t)
    #pragma unroll
    for (int a = 0; a < 4; ++a) {
      float4 f = *reinterpret_cast<const float4*>(&pool_lds[p][lh][l31][(t * 4 + a) * 4]);
      acc[t][4 * a + 0] += f.x; acc[t][4 * a + 1] += f.y;
      acc[t][4 * a + 2] += f.z; acc[t][4 * a + 3] += f.w;
    }

  // ---- pooled += maskT @ b3 (bias of masked sum), 8 MFMA ----
  {
    f16x8 mf[2];
    #pragma unroll
    for (int ks = 0; ks < 2; ++ks) {
      unsigned w[4];
      #pragma unroll
      for (int i = 0; i < 4; ++i) {
        int d0 = ks * 16 + lh * 8 + 2 * i;
        w[i] = (((mword >> d0) & 1u) ? 0x3C00u : 0u) |
               (((mword >> (d0 + 1)) & 1u) ? 0x3C000000u : 0u);
      }
      uintx4 ww = {w[0], w[1], w[2], w[3]};
      mf[ks] = __builtin_bit_cast(f16x8, ww);
    }
    const f16_t* b3t = ws + B3T_OFF + l31 * 32 + lh * 8;
    #pragma unroll
    for (int t = 0; t < 4; ++t)
      #pragma unroll
      for (int ks = 0; ks < 2; ++ks) {
        f16x8 bf = *reinterpret_cast<const f16x8*>(b3t + t * 1024 + ks * 16);
        acc[t] = __builtin_amdgcn_mfma_f32_32x32x16_f16(bf, mf[ks], acc[t], 0, 0, 0);
      }
  }

  // ---- R1 (swapped): r1^T = rW1T x pooled^T, K=128 ----
  f16x8 poolf[8];
  xpose2(acc[0], xrow0, lh, poolf[0], poolf[1]);
  xpose2(acc[1], xrow1, lh, poolf[2], poolf[3]);
  xpose2(acc[2], xrow0, lh, poolf[4], poolf[5]);
  xpose2(acc[3], xrow1, lh, poolf[6], poolf[7]);
  f32x16 r1[2];
  #pragma unroll
  for (int t = 0; t < 2; ++t)
    #pragma unroll
    for (int a = 0; a < 4; ++a) {
      float4 bv = *reinterpret_cast<const float4*>(&rb_lds[t * 32 + a * 8 + lh * 4]);
      r1[t][4 * a + 0] = bv.x; r1[t][4 * a + 1] = bv.y;
      r1[t][4 * a + 2] = bv.z; r1[t][4 * a + 3] = bv.w;
    }
  {
    const f16_t* rw1 = ws + RW1T_OFF + l31 * 128 + lh * 8;
    #pragma unroll
    for (int t = 0; t < 2; ++t)
      #pragma unroll
      for (int ks = 0; ks < 8; ++ks) {
        f16x8 wf = *reinterpret_cast<const f16x8*>(rw1 + t * 4096 + ks * 16);
        r1[t] = __builtin_amdgcn_mfma_f32_32x32x16_f16(wf, poolf[ks], r1[t], 0, 0, 0);
      }
  }
  #pragma unroll
  for (int t = 0; t < 2; ++t)
    #pragma unroll
    for (int r = 0; r < 16; ++r) r1[t][r] = fmaxf(r1[t][r], 0.f);

  // ---- R2 (swapped): r2^T = rW2T x r1^T, K=64 ----
  f16x8 r1f[4];
  xpose2(r1[0], xrow0, lh, r1f[0], r1f[1]);
  xpose2(r1[1], xrow1, lh, r1f[2], r1f[3]);
  f32x16 r2[2];
  #pragma unroll
  for (int t = 0; t < 2; ++t)
    #pragma unroll
    for (int a = 0; a < 4; ++a) {
      float4 bv = *reinterpret_cast<const float4*>(&rb_lds[64 + t * 32 + a * 8 + lh * 4]);
      r2[t][4 * a + 0] = bv.x; r2[t][4 * a + 1] = bv.y;
      r2[t][4 * a + 2] = bv.z; r2[t][4 * a + 3] = bv.w;
    }
  {
    const f16_t* rw2 = ws + RW2T_OFF + l31 * 64 + lh * 8;
    #pragma unroll
    for (int t = 0; t < 2; ++t)
      #pragma unroll
      for (int ks = 0; ks < 4; ++ks) {
        f16x8 wf = *reinterpret_cast<const f16x8*>(rw2 + t * 2048 + ks * 16);
        r2[t] = __builtin_amdgcn_mfma_f32_32x32x16_f16(wf, r1f[ks], r2[t], 0, 0, 0);
      }
  }
  #pragma unroll
  for (int t = 0; t < 2; ++t)
    #pragma unroll
    for (int r = 0; r < 16; ++r) r2[t][r] = fmaxf(r2[t][r], 0.f);

  // ---- R3 (NON-swapped for coalesced stores): o = r2 @ rW3, N=128 ----
  f16x8 r2f[4];
  xpose2(r2[0], xrow0, lh, r2f[0], r2f[1]);
  xpose2(r2[1], xrow1, lh, r2f[2], r2f[3]);
  f32x16 oacc[4] = {};
  {
    const f16_t* rw3 = ws + RW3T_OFF + l31 * 64 + lh * 8;
    #pragma unroll
    for (int nt = 0; nt < 4; ++nt)
      #pragma unroll
      for (int ks = 0; ks < 4; ++ks) {
        f16x8 wf = *reinterpret_cast<const f16x8*>(rw3 + nt * 2048 + ks * 16);
        oacc[nt] = __builtin_amdgcn_mfma_f32_32x32x16_f16(r2f[ks], wf, oacc[nt], 0, 0, 0);
      }
  }
  const int rowb = row0 + p * 32;
  #pragma unroll
  for (int nt = 0; nt < 4; ++nt) {
    float rbv = rb_lds[128 + nt * 32 + l31];
    #pragma unroll
    for (int r = 0; r < 16; ++r) {
      int rl = (r & 3) + 8 * (r >> 2) + 4 * lh;
      size_t grow = (size_t)(rowb + rl);
      float v = oacc[nt][r] + rbv;
      if (nt < 2) {
        out[grow * 64 + nt * 32 + l31] = v;
      } else {
        float sp = fmaxf(v, 0.f) + __logf(1.f + __expf(-fabsf(v)));
        out[(size_t)SIG_OFF + grow * 64 + (nt - 2) * 32 + l31] = sp;
      }
    }
  }
}

extern "C" void kernel_launch(void* const* d_in, const int* in_sizes, int n_in,
                              void* d_out, int out_size, void* d_ws, size_t ws_size,
                              hipStream_t stream) {
  const float* x    = (const float*)d_in[0];
  const int*   mask = (const int*)d_in[1];
  const float* W1   = (const float*)d_in[2];
  const float* b1   = (const float*)d_in[3];
  const float* W2   = (const float*)d_in[4];
  const float* b2   = (const float*)d_in[5];
  const float* W3   = (const float*)d_in[6];
  const float* b3   = (const float*)d_in[7];
  const float* rW1  = (const float*)d_in[8];
  const float* rb1  = (const float*)d_in[9];
  const float* rW2  = (const float*)d_in[10];
  const float* rb2  = (const float*)d_in[11];
  const float* rW3  = (const float*)d_in[12];
  const float* rb3  = (const float*)d_in[13];
  float* out = (float*)d_out;
  f16_t* ws = (f16_t*)d_ws;

  convert_weights<<<256, 256, 0, stream>>>(W1, b1, W2, W3, b3, rW1, rW2, rW3, ws);
  indexnet_main<<<NROWS / 64, 256, 0, stream>>>(
      x, mask, b2, rb1, rb2, rb3, ws, out);
}

// Round 4
// 64.002 us; speedup vs baseline: 2.4611x; 1.7720x over previous
//
#include <hip/hip_runtime.h>
#include <hip/hip_bf16.h>
#include <math.h>

typedef _Float16 f16_t;
typedef _Float16 f16x8 __attribute__((ext_vector_type(8)));
typedef float f32x16 __attribute__((ext_vector_type(16)));
typedef unsigned int uintx4 __attribute__((ext_vector_type(4)));
typedef unsigned int uintx2 __attribute__((ext_vector_type(2)));

#define NROWS 32768
#define DD 32
#define SIG_OFF (NROWS * 64)

// ---------------- ws layout (f16 elements) ----------------
// All GEMM weights are stored in PER-WAVE FRAGMENT-LOAD ORDER:
//   [tile][ks][lane(0..63)][j(0..7)]  -> each fragment load is lane*16B,
// fully coalesced (16 cache lines / instr instead of ~56-line gathers).
// Fragment element semantics: lane = l31 + 32*lh; n = tile*32 + l31;
//   k = ks*16 + lh*8 + j.
#define PERD_STRIDE 12416          // per-d super-block: wf2 4096 | wf3 8192 | w1 64 | b1 64
#define PERD_OFF   0
#define RW1F_OFF   397312          // 2t x 8ks x 512 = 8192   (rW1[k][n], k<128)
#define RW2F_OFF   405504          // 2t x 4ks x 512 = 4096   (rW2[k][n], k<64)
#define RW3F_OFF   409600          // 4nt x 4ks x 512 = 8192  (rW3[k][n], n<128)
#define B3F_OFF    417792          // 4t x 2ks x 512 = 4096   (b3[d][n] as B-frag, "k"=d)
#define WS_ELEMS   421888

__global__ void convert_weights(const float* __restrict__ W1,
                                const float* __restrict__ b1,
                                const float* __restrict__ W2,
                                const float* __restrict__ W3,
                                const float* __restrict__ b3,
                                const float* __restrict__ rW1,
                                const float* __restrict__ rW2,
                                const float* __restrict__ rW3,
                                f16_t* __restrict__ ws) {
  for (int i = blockIdx.x * blockDim.x + threadIdx.x; i < WS_ELEMS;
       i += gridDim.x * blockDim.x) {
    float v;
    if (i < RW1F_OFF) {
      int d = i / PERD_STRIDE;
      int r = i - d * PERD_STRIDE;
      if (r < 4096) {                 // wf2 fragments: W2[d][k][n], n<64
        int t = r >> 11, ks = (r >> 9) & 3, lane = (r >> 3) & 63, j = r & 7;
        int n = t * 32 + (lane & 31);
        int k = ks * 16 + (lane >> 5) * 8 + j;
        v = W2[(d * 64 + k) * 64 + n];
      } else if (r < 12288) {         // wf3 fragments: W3[d][k][n], n<128
        int r2 = r - 4096;
        int t = r2 >> 11, ks = (r2 >> 9) & 3, lane = (r2 >> 3) & 63, j = r2 & 7;
        int n = t * 32 + (lane & 31);
        int k = ks * 16 + (lane >> 5) * 8 + j;
        v = W3[(d * 64 + k) * 128 + n];
      } else if (r < 12352) {         // w1 (linear, broadcast-read)
        v = W1[d * 64 + (r - 12288)];
      } else {                        // b1 (linear)
        v = b1[d * 64 + (r - 12352)];
      }
    } else if (i < RW2F_OFF) {        // rW1 fragments, k<128
      int i2 = i - RW1F_OFF;
      int t = i2 >> 12, ks = (i2 >> 9) & 7, lane = (i2 >> 3) & 63, j = i2 & 7;
      int n = t * 32 + (lane & 31);
      int k = ks * 16 + (lane >> 5) * 8 + j;
      v = rW1[k * 64 + n];
    } else if (i < RW3F_OFF) {        // rW2 fragments, k<64
      int i2 = i - RW2F_OFF;
      int t = i2 >> 11, ks = (i2 >> 9) & 3, lane = (i2 >> 3) & 63, j = i2 & 7;
      int n = t * 32 + (lane & 31);
      int k = ks * 16 + (lane >> 5) * 8 + j;
      v = rW2[k * 64 + n];
    } else if (i < B3F_OFF) {         // rW3 fragments, output col n<128, k<64
      int i2 = i - RW3F_OFF;
      int nt = i2 >> 11, ks = (i2 >> 9) & 3, lane = (i2 >> 3) & 63, j = i2 & 7;
      int n = nt * 32 + (lane & 31);
      int k = ks * 16 + (lane >> 5) * 8 + j;
      v = rW3[k * 128 + n];
    } else {                          // b3 as B-fragment: "k" axis = d (32)
      int i2 = i - B3F_OFF;
      int t = i2 >> 10, ks = (i2 >> 9) & 1, lane = (i2 >> 3) & 63, j = i2 & 7;
      int n = t * 32 + (lane & 31);
      int dsrc = ks * 16 + (lane >> 5) * 8 + j;
      v = b3[dsrc * 128 + n];
    }
    ws[i] = (f16_t)v;
  }
}

// Transpose a swapped-GEMM C tile (lane = data-row l31, regs = 16 n-values:
// n = (reg&3)+8*(reg>>2)+4*lh) into two B fragments (lane supplies
// n = 16*kk + 8*lh + j, j=0..7 contiguous) via a PER-WAVE private LDS
// round-trip. Within-wave ds_write->ds_read ordering is a compiler-visible
// LDS dependence (lgkmcnt inserted automatically) -- no barrier needed.
__device__ __forceinline__ void xpose2(const f32x16& c, unsigned* row, int lh,
                                       f16x8& o0, f16x8& o1) {
  #pragma unroll
  for (int a = 0; a < 4; ++a) {
    uintx2 w;
    w.x = __builtin_bit_cast(unsigned, __builtin_amdgcn_cvt_pkrtz(c[4 * a + 0], c[4 * a + 1]));
    w.y = __builtin_bit_cast(unsigned, __builtin_amdgcn_cvt_pkrtz(c[4 * a + 2], c[4 * a + 3]));
    *reinterpret_cast<uintx2*>(row + 4 * a + 2 * lh) = w;
  }
  uintx2 ra = *reinterpret_cast<const uintx2*>(row + 4 * lh);
  uintx2 rb = *reinterpret_cast<const uintx2*>(row + 4 * lh + 2);
  uintx2 rc = *reinterpret_cast<const uintx2*>(row + 8 + 4 * lh);
  uintx2 rd = *reinterpret_cast<const uintx2*>(row + 8 + 4 * lh + 2);
  uintx4 w0 = {ra.x, ra.y, rb.x, rb.y};
  uintx4 w1 = {rc.x, rc.y, rd.x, rd.y};
  o0 = __builtin_bit_cast(f16x8, w0);
  o1 = __builtin_bit_cast(f16x8, w1);
}

// Block = 256 thr = 4 waves = 2 pairs. Pair p owns rows blk*64+p*32+(lane&31).
// Wave parity q: d-range [q*16, q*16+16). All layer GEMMs are computed
// swapped (C' = W^T x act^T) so activations stay lane-local; transposes via
// per-wave LDS round-trip (xpose2). Pool accumulates inside the GEMM2 MFMA
// accumulator across d (mask folded into h2). Barriers: 2 total.
__launch_bounds__(256, 2)
__global__ void indexnet_main(const float* __restrict__ x,
                              const int* __restrict__ mask,
                              const float* __restrict__ b2,
                              const float* __restrict__ rb1,
                              const float* __restrict__ rb2,
                              const float* __restrict__ rb3,
                              const f16_t* __restrict__ ws,
                              float* __restrict__ out) {
  __shared__ float x_lds[64][33];
  __shared__ float b2_lds[32][64];
  __shared__ float rb_lds[256];                        // rb1 | rb2 | rb3
  __shared__ float pool_lds[2][2][32][68];             // [pair][lh][l31][64+pad]
  __shared__ __align__(16) unsigned xp_lds[4][2][32][18];  // per-wave xpose scratch

  const int tid = threadIdx.x;
  const int lane = tid & 63;
  const int wid = tid >> 6;
  const int p = wid >> 1;          // pair (row group)
  const int q = wid & 1;           // d-range half
  const int l31 = lane & 31;
  const int lh = lane >> 5;
  const int row0 = blockIdx.x * 64;
  const int lane16 = lane * 8;     // f16 offset of this lane's 16B fragment chunk

  unsigned* xrow0 = &xp_lds[wid][0][l31][0];
  unsigned* xrow1 = &xp_lds[wid][1][l31][0];

  // ---- stage x tile [64][32] ----
  {
    const float4* src = reinterpret_cast<const float4*>(x + (size_t)row0 * DD);
    float4 a = src[tid * 2];
    float4 b = src[tid * 2 + 1];
    int r = tid >> 2, c = (tid & 3) * 8;
    x_lds[r][c + 0] = a.x; x_lds[r][c + 1] = a.y; x_lds[r][c + 2] = a.z; x_lds[r][c + 3] = a.w;
    x_lds[r][c + 4] = b.x; x_lds[r][c + 5] = b.y; x_lds[r][c + 6] = b.z; x_lds[r][c + 7] = b.w;
  }
  // ---- stage b2 [32][64] (flat copy) ----
  {
    float4* dst = reinterpret_cast<float4*>(&b2_lds[0][0]);
    const float4* src = reinterpret_cast<const float4*>(b2);
    dst[tid * 2] = src[tid * 2];
    dst[tid * 2 + 1] = src[tid * 2 + 1];
  }
  // ---- stage readout biases ----
  if (tid < 64)       rb_lds[tid] = rb1[tid];
  else if (tid < 128) rb_lds[tid] = rb2[tid - 64];
  else                rb_lds[tid] = rb3[tid - 128];

  // ---- per-lane mask word for own row ----
  unsigned mword = 0;
  {
    const int4* mrow = reinterpret_cast<const int4*>(mask + (size_t)(row0 + p * 32 + l31) * DD);
    #pragma unroll
    for (int c4 = 0; c4 < 8; ++c4) {
      int4 m = mrow[c4];
      mword |= (m.x != 0 ? 1u : 0u) << (4 * c4);
      mword |= (m.y != 0 ? 1u : 0u) << (4 * c4 + 1);
      mword |= (m.z != 0 ? 1u : 0u) << (4 * c4 + 2);
      mword |= (m.w != 0 ? 1u : 0u) << (4 * c4 + 3);
    }
  }
  __syncthreads();   // barrier #1

  f32x16 acc[4] = {};     // pooled^T accumulator: tile t -> n = 32t + rl, lane = row
  const int dbase = q * 16;

  for (int dd = 0; dd < 16; ++dd) {
    const int d = dbase + dd;
    const f16_t* base = ws + (size_t)d * PERD_STRIDE;
    // coalesced fragment loads: lane*16B within each 1KB chunk
    f16x8 wf2[2][4];
    #pragma unroll
    for (int t = 0; t < 2; ++t)
      #pragma unroll
      for (int ks = 0; ks < 4; ++ks)
        wf2[t][ks] = *reinterpret_cast<const f16x8*>(base + (t * 4 + ks) * 512 + lane16);

    // ---- h1 fragments in packed f16: h1[l31][16ks+8lh+j] ----
    float xv = x_lds[p * 32 + l31][d];
    f16_t xh = (f16_t)xv;
    f16x8 xv8 = {xh, xh, xh, xh, xh, xh, xh, xh};
    f16x8 h1f[4];
    const f16_t* w1p = base + 12288 + lh * 8;
    const f16_t* b1p = base + 12352 + lh * 8;
    #pragma unroll
    for (int ks = 0; ks < 4; ++ks) {
      f16x8 w1 = *reinterpret_cast<const f16x8*>(w1p + ks * 16);
      f16x8 bb = *reinterpret_cast<const f16x8*>(b1p + ks * 16);
      f16x8 h = xv8 * w1 + bb;
      h1f[ks] = __builtin_elementwise_max(h, (f16x8)(f16_t)0);
    }

    // ---- GEMM1 (swapped): h2^T = W2T x h1^T, acc init = b2 ----
    f32x16 hacc[2];
    #pragma unroll
    for (int t = 0; t < 2; ++t)
      #pragma unroll
      for (int a = 0; a < 4; ++a) {
        float4 bv = *reinterpret_cast<const float4*>(&b2_lds[d][t * 32 + a * 8 + lh * 4]);
        hacc[t][4 * a + 0] = bv.x; hacc[t][4 * a + 1] = bv.y;
        hacc[t][4 * a + 2] = bv.z; hacc[t][4 * a + 3] = bv.w;
      }
    #pragma unroll
    for (int ks = 0; ks < 4; ++ks) {
      hacc[0] = __builtin_amdgcn_mfma_f32_32x32x16_f16(wf2[0][ks], h1f[ks], hacc[0], 0, 0, 0);
      hacc[1] = __builtin_amdgcn_mfma_f32_32x32x16_f16(wf2[1][ks], h1f[ks], hacc[1], 0, 0, 0);
    }
    // relu + mask (lane = data row for C cols)
    const bool mb = (mword >> d) & 1u;
    #pragma unroll
    for (int t = 0; t < 2; ++t)
      #pragma unroll
      for (int r = 0; r < 16; ++r) {
        float v = fmaxf(hacc[t][r], 0.f);
        hacc[t][r] = mb ? v : 0.f;
      }
    // LDS-based in-wave transpose -> GEMM2 B fragments
    f16x8 pf[4];
    xpose2(hacc[0], xrow0, lh, pf[0], pf[1]);
    xpose2(hacc[1], xrow1, lh, pf[2], pf[3]);

    // ---- GEMM2 (swapped): pooled^T += W3T x (m*h2)^T  (acc across d) ----
    const f16_t* w3f = base + 4096;
    #pragma unroll
    for (int t = 0; t < 4; ++t)
      #pragma unroll
      for (int ks = 0; ks < 4; ++ks) {
        f16x8 wf = *reinterpret_cast<const f16x8*>(w3f + (t * 4 + ks) * 512 + lane16);
        acc[t] = __builtin_amdgcn_mfma_f32_32x32x16_f16(wf, pf[ks], acc[t], 0, 0, 0);
      }
  }

  // ---- pool combine across the wave pair ----
  if (q == 1) {
    #pragma unroll
    for (int t = 0; t < 4; ++t)
      #pragma unroll
      for (int a = 0; a < 4; ++a) {
        float4 f = {acc[t][4 * a], acc[t][4 * a + 1], acc[t][4 * a + 2], acc[t][4 * a + 3]};
        *reinterpret_cast<float4*>(&pool_lds[p][lh][l31][(t * 4 + a) * 4]) = f;
      }
  }
  __syncthreads();   // barrier #2
  if (q == 1) return;

  #pragma unroll
  for (int t = 0; t < 4; ++t)
    #pragma unroll
    for (int a = 0; a < 4; ++a) {
      float4 f = *reinterpret_cast<const float4*>(&pool_lds[p][lh][l31][(t * 4 + a) * 4]);
      acc[t][4 * a + 0] += f.x; acc[t][4 * a + 1] += f.y;
      acc[t][4 * a + 2] += f.z; acc[t][4 * a + 3] += f.w;
    }

  // ---- pooled += maskT @ b3 (bias of masked sum), 8 MFMA ----
  {
    f16x8 mf[2];
    #pragma unroll
    for (int ks = 0; ks < 2; ++ks) {
      unsigned w[4];
      #pragma unroll
      for (int i = 0; i < 4; ++i) {
        int d0 = ks * 16 + lh * 8 + 2 * i;
        w[i] = (((mword >> d0) & 1u) ? 0x3C00u : 0u) |
               (((mword >> (d0 + 1)) & 1u) ? 0x3C000000u : 0u);
      }
      uintx4 ww = {w[0], w[1], w[2], w[3]};
      mf[ks] = __builtin_bit_cast(f16x8, ww);
    }
    const f16_t* b3f = ws + B3F_OFF;
    #pragma unroll
    for (int t = 0; t < 4; ++t)
      #pragma unroll
      for (int ks = 0; ks < 2; ++ks) {
        f16x8 bf = *reinterpret_cast<const f16x8*>(b3f + (t * 2 + ks) * 512 + lane16);
        acc[t] = __builtin_amdgcn_mfma_f32_32x32x16_f16(bf, mf[ks], acc[t], 0, 0, 0);
      }
  }

  // ---- R1 (swapped): r1^T = rW1T x pooled^T, K=128 ----
  f16x8 poolf[8];
  xpose2(acc[0], xrow0, lh, poolf[0], poolf[1]);
  xpose2(acc[1], xrow1, lh, poolf[2], poolf[3]);
  xpose2(acc[2], xrow0, lh, poolf[4], poolf[5]);
  xpose2(acc[3], xrow1, lh, poolf[6], poolf[7]);
  f32x16 r1[2];
  #pragma unroll
  for (int t = 0; t < 2; ++t)
    #pragma unroll
    for (int a = 0; a < 4; ++a) {
      float4 bv = *reinterpret_cast<const float4*>(&rb_lds[t * 32 + a * 8 + lh * 4]);
      r1[t][4 * a + 0] = bv.x; r1[t][4 * a + 1] = bv.y;
      r1[t][4 * a + 2] = bv.z; r1[t][4 * a + 3] = bv.w;
    }
  {
    const f16_t* rw1 = ws + RW1F_OFF;
    #pragma unroll
    for (int t = 0; t < 2; ++t)
      #pragma unroll
      for (int ks = 0; ks < 8; ++ks) {
        f16x8 wf = *reinterpret_cast<const f16x8*>(rw1 + (t * 8 + ks) * 512 + lane16);
        r1[t] = __builtin_amdgcn_mfma_f32_32x32x16_f16(wf, poolf[ks], r1[t], 0, 0, 0);
      }
  }
  #pragma unroll
  for (int t = 0; t < 2; ++t)
    #pragma unroll
    for (int r = 0; r < 16; ++r) r1[t][r] = fmaxf(r1[t][r], 0.f);

  // ---- R2 (swapped): r2^T = rW2T x r1^T, K=64 ----
  f16x8 r1f[4];
  xpose2(r1[0], xrow0, lh, r1f[0], r1f[1]);
  xpose2(r1[1], xrow1, lh, r1f[2], r1f[3]);
  f32x16 r2[2];
  #pragma unroll
  for (int t = 0; t < 2; ++t)
    #pragma unroll
    for (int a = 0; a < 4; ++a) {
      float4 bv = *reinterpret_cast<const float4*>(&rb_lds[64 + t * 32 + a * 8 + lh * 4]);
      r2[t][4 * a + 0] = bv.x; r2[t][4 * a + 1] = bv.y;
      r2[t][4 * a + 2] = bv.z; r2[t][4 * a + 3] = bv.w;
    }
  {
    const f16_t* rw2 = ws + RW2F_OFF;
    #pragma unroll
    for (int t = 0; t < 2; ++t)
      #pragma unroll
      for (int ks = 0; ks < 4; ++ks) {
        f16x8 wf = *reinterpret_cast<const f16x8*>(rw2 + (t * 4 + ks) * 512 + lane16);
        r2[t] = __builtin_amdgcn_mfma_f32_32x32x16_f16(wf, r1f[ks], r2[t], 0, 0, 0);
      }
  }
  #pragma unroll
  for (int t = 0; t < 2; ++t)
    #pragma unroll
    for (int r = 0; r < 16; ++r) r2[t][r] = fmaxf(r2[t][r], 0.f);

  // ---- R3 (NON-swapped for coalesced stores): o = r2 @ rW3, N=128 ----
  f16x8 r2f[4];
  xpose2(r2[0], xrow0, lh, r2f[0], r2f[1]);
  xpose2(r2[1], xrow1, lh, r2f[2], r2f[3]);
  f32x16 oacc[4] = {};
  {
    const f16_t* rw3 = ws + RW3F_OFF;
    #pragma unroll
    for (int nt = 0; nt < 4; ++nt)
      #pragma unroll
      for (int ks = 0; ks < 4; ++ks) {
        f16x8 wf = *reinterpret_cast<const f16x8*>(rw3 + (nt * 4 + ks) * 512 + lane16);
        oacc[nt] = __builtin_amdgcn_mfma_f32_32x32x16_f16(r2f[ks], wf, oacc[nt], 0, 0, 0);
      }
  }
  const int rowb = row0 + p * 32;
  #pragma unroll
  for (int nt = 0; nt < 4; ++nt) {
    float rbv = rb_lds[128 + nt * 32 + l31];
    #pragma unroll
    for (int r = 0; r < 16; ++r) {
      int rl = (r & 3) + 8 * (r >> 2) + 4 * lh;
      size_t grow = (size_t)(rowb + rl);
      float v = oacc[nt][r] + rbv;
      if (nt < 2) {
        out[grow * 64 + nt * 32 + l31] = v;
      } else {
        float sp = fmaxf(v, 0.f) + __logf(1.f + __expf(-fabsf(v)));
        out[(size_t)SIG_OFF + grow * 64 + (nt - 2) * 32 + l31] = sp;
      }
    }
  }
}

extern "C" void kernel_launch(void* const* d_in, const int* in_sizes, int n_in,
                              void* d_out, int out_size, void* d_ws, size_t ws_size,
                              hipStream_t stream) {
  const float* x    = (const float*)d_in[0];
  const int*   mask = (const int*)d_in[1];
  const float* W1   = (const float*)d_in[2];
  const float* b1   = (const float*)d_in[3];
  const float* W2   = (const float*)d_in[4];
  const float* b2   = (const float*)d_in[5];
  const float* W3   = (const float*)d_in[6];
  const float* b3   = (const float*)d_in[7];
  const float* rW1  = (const float*)d_in[8];
  const float* rb1  = (const float*)d_in[9];
  const float* rW2  = (const float*)d_in[10];
  const float* rb2  = (const float*)d_in[11];
  const float* rW3  = (const float*)d_in[12];
  const float* rb3  = (const float*)d_in[13];
  float* out = (float*)d_out;
  f16_t* ws = (f16_t*)d_ws;

  convert_weights<<<256, 256, 0, stream>>>(W1, b1, W2, W3, b3, rW1, rW2, rW3, ws);
  indexnet_main<<<NROWS / 64, 256, 0, stream>>>(
      x, mask, b2, rb1, rb2, rb3, ws, out);
}

// Round 5
// 63.976 us; speedup vs baseline: 2.4621x; 1.0004x over previous
//
#include <hip/hip_runtime.h>
#include <hip/hip_bf16.h>
#include <math.h>

typedef _Float16 f16_t;
typedef _Float16 f16x8 __attribute__((ext_vector_type(8)));
typedef float f32x16 __attribute__((ext_vector_type(16)));
typedef unsigned int uintx4 __attribute__((ext_vector_type(4)));
typedef unsigned int uintx2 __attribute__((ext_vector_type(2)));

#define NROWS 32768
#define DD 32
#define SIG_OFF (NROWS * 64)

// ---------------- ws layout (f16 elements) ----------------
// All GEMM weights are stored in PER-WAVE FRAGMENT-LOAD ORDER:
//   [tile][ks][lane(0..63)][j(0..7)]  -> each fragment load is lane*16B,
// fully coalesced (16 cache lines / instr instead of ~56-line gathers).
// Fragment element semantics: lane = l31 + 32*lh; n = tile*32 + l31;
//   k = ks*16 + lh*8 + j.
#define PERD_STRIDE 12416          // per-d super-block: wf2 4096 | wf3 8192 | w1 64 | b1 64
#define PERD_OFF   0
#define RW1F_OFF   397312          // 2t x 8ks x 512 = 8192   (rW1[k][n], k<128)
#define RW2F_OFF   405504          // 2t x 4ks x 512 = 4096   (rW2[k][n], k<64)
#define RW3F_OFF   409600          // 4nt x 4ks x 512 = 8192  (rW3[k][n], n<128)
#define B3F_OFF    417792          // 4t x 2ks x 512 = 4096   (b3[d][n] as B-frag, "k"=d)
#define WS_ELEMS   421888

__global__ void convert_weights(const float* __restrict__ W1,
                                const float* __restrict__ b1,
                                const float* __restrict__ W2,
                                const float* __restrict__ W3,
                                const float* __restrict__ b3,
                                const float* __restrict__ rW1,
                                const float* __restrict__ rW2,
                                const float* __restrict__ rW3,
                                f16_t* __restrict__ ws) {
  for (int i = blockIdx.x * blockDim.x + threadIdx.x; i < WS_ELEMS;
       i += gridDim.x * blockDim.x) {
    float v;
    if (i < RW1F_OFF) {
      int d = i / PERD_STRIDE;
      int r = i - d * PERD_STRIDE;
      if (r < 4096) {                 // wf2 fragments: W2[d][k][n], n<64
        int t = r >> 11, ks = (r >> 9) & 3, lane = (r >> 3) & 63, j = r & 7;
        int n = t * 32 + (lane & 31);
        int k = ks * 16 + (lane >> 5) * 8 + j;
        v = W2[(d * 64 + k) * 64 + n];
      } else if (r < 12288) {         // wf3 fragments: W3[d][k][n], n<128
        int r2 = r - 4096;
        int t = r2 >> 11, ks = (r2 >> 9) & 3, lane = (r2 >> 3) & 63, j = r2 & 7;
        int n = t * 32 + (lane & 31);
        int k = ks * 16 + (lane >> 5) * 8 + j;
        v = W3[(d * 64 + k) * 128 + n];
      } else if (r < 12352) {         // w1 (linear, broadcast-read)
        v = W1[d * 64 + (r - 12288)];
      } else {                        // b1 (linear)
        v = b1[d * 64 + (r - 12352)];
      }
    } else if (i < RW2F_OFF) {        // rW1 fragments, k<128
      int i2 = i - RW1F_OFF;
      int t = i2 >> 12, ks = (i2 >> 9) & 7, lane = (i2 >> 3) & 63, j = i2 & 7;
      int n = t * 32 + (lane & 31);
      int k = ks * 16 + (lane >> 5) * 8 + j;
      v = rW1[k * 64 + n];
    } else if (i < RW3F_OFF) {        // rW2 fragments, k<64
      int i2 = i - RW2F_OFF;
      int t = i2 >> 11, ks = (i2 >> 9) & 3, lane = (i2 >> 3) & 63, j = i2 & 7;
      int n = t * 32 + (lane & 31);
      int k = ks * 16 + (lane >> 5) * 8 + j;
      v = rW2[k * 64 + n];
    } else if (i < B3F_OFF) {         // rW3 fragments, output col n<128, k<64
      int i2 = i - RW3F_OFF;
      int nt = i2 >> 11, ks = (i2 >> 9) & 3, lane = (i2 >> 3) & 63, j = i2 & 7;
      int n = nt * 32 + (lane & 31);
      int k = ks * 16 + (lane >> 5) * 8 + j;
      v = rW3[k * 128 + n];
    } else {                          // b3 as B-fragment: "k" axis = d (32)
      int i2 = i - B3F_OFF;
      int t = i2 >> 10, ks = (i2 >> 9) & 1, lane = (i2 >> 3) & 63, j = i2 & 7;
      int n = t * 32 + (lane & 31);
      int dsrc = ks * 16 + (lane >> 5) * 8 + j;
      v = b3[dsrc * 128 + n];
    }
    ws[i] = (f16_t)v;
  }
}

// Transpose a swapped-GEMM C tile (lane = data-row l31, regs = 16 n-values:
// n = (reg&3)+8*(reg>>2)+4*lh) into two B fragments (lane supplies
// n = 16*kk + 8*lh + j, j=0..7 contiguous) via a PER-WAVE private LDS
// round-trip. Within-wave ds_write->ds_read ordering is a compiler-visible
// LDS dependence (lgkmcnt inserted automatically) -- no barrier needed.
__device__ __forceinline__ void xpose2(const f32x16& c, unsigned* row, int lh,
                                       f16x8& o0, f16x8& o1) {
  #pragma unroll
  for (int a = 0; a < 4; ++a) {
    uintx2 w;
    w.x = __builtin_bit_cast(unsigned, __builtin_amdgcn_cvt_pkrtz(c[4 * a + 0], c[4 * a + 1]));
    w.y = __builtin_bit_cast(unsigned, __builtin_amdgcn_cvt_pkrtz(c[4 * a + 2], c[4 * a + 3]));
    *reinterpret_cast<uintx2*>(row + 4 * a + 2 * lh) = w;
  }
  uintx2 ra = *reinterpret_cast<const uintx2*>(row + 4 * lh);
  uintx2 rb = *reinterpret_cast<const uintx2*>(row + 4 * lh + 2);
  uintx2 rc = *reinterpret_cast<const uintx2*>(row + 8 + 4 * lh);
  uintx2 rd = *reinterpret_cast<const uintx2*>(row + 8 + 4 * lh + 2);
  uintx4 w0 = {ra.x, ra.y, rb.x, rb.y};
  uintx4 w1 = {rc.x, rc.y, rd.x, rd.y};
  o0 = __builtin_bit_cast(f16x8, w0);
  o1 = __builtin_bit_cast(f16x8, w1);
}

// Block = 256 thr = 4 waves = 2 pairs. Pair p owns rows blk*64+p*32+(lane&31).
// Wave parity q: d-range [q*16, q*16+16). All layer GEMMs are computed
// swapped (C' = W^T x act^T) so activations stay lane-local; transposes via
// per-wave LDS round-trip (xpose2). Pool accumulates inside the GEMM2 MFMA
// accumulator across d (mask folded into h2). Barriers: 2 total.
__launch_bounds__(256, 2)
__global__ void indexnet_main(const float* __restrict__ x,
                              const int* __restrict__ mask,
                              const float* __restrict__ b2,
                              const float* __restrict__ rb1,
                              const float* __restrict__ rb2,
                              const float* __restrict__ rb3,
                              const f16_t* __restrict__ ws,
                              float* __restrict__ out) {
  __shared__ float x_lds[64][33];
  __shared__ float b2_lds[32][64];
  __shared__ float rb_lds[256];                        // rb1 | rb2 | rb3
  __shared__ float pool_lds[2][2][32][68];             // [pair][lh][l31][64+pad]
  __shared__ __align__(16) unsigned xp_lds[4][2][32][18];  // per-wave xpose scratch

  const int tid = threadIdx.x;
  const int lane = tid & 63;
  const int wid = tid >> 6;
  const int p = wid >> 1;          // pair (row group)
  const int q = wid & 1;           // d-range half
  const int l31 = lane & 31;
  const int lh = lane >> 5;
  const int row0 = blockIdx.x * 64;
  const int lane16 = lane * 8;     // f16 offset of this lane's 16B fragment chunk

  unsigned* xrow0 = &xp_lds[wid][0][l31][0];
  unsigned* xrow1 = &xp_lds[wid][1][l31][0];

  // ---- stage x tile [64][32] ----
  {
    const float4* src = reinterpret_cast<const float4*>(x + (size_t)row0 * DD);
    float4 a = src[tid * 2];
    float4 b = src[tid * 2 + 1];
    int r = tid >> 2, c = (tid & 3) * 8;
    x_lds[r][c + 0] = a.x; x_lds[r][c + 1] = a.y; x_lds[r][c + 2] = a.z; x_lds[r][c + 3] = a.w;
    x_lds[r][c + 4] = b.x; x_lds[r][c + 5] = b.y; x_lds[r][c + 6] = b.z; x_lds[r][c + 7] = b.w;
  }
  // ---- stage b2 [32][64] (flat copy) ----
  {
    float4* dst = reinterpret_cast<float4*>(&b2_lds[0][0]);
    const float4* src = reinterpret_cast<const float4*>(b2);
    dst[tid * 2] = src[tid * 2];
    dst[tid * 2 + 1] = src[tid * 2 + 1];
  }
  // ---- stage readout biases ----
  if (tid < 64)       rb_lds[tid] = rb1[tid];
  else if (tid < 128) rb_lds[tid] = rb2[tid - 64];
  else                rb_lds[tid] = rb3[tid - 128];

  // ---- per-lane mask word for own row ----
  unsigned mword = 0;
  {
    const int4* mrow = reinterpret_cast<const int4*>(mask + (size_t)(row0 + p * 32 + l31) * DD);
    #pragma unroll
    for (int c4 = 0; c4 < 8; ++c4) {
      int4 m = mrow[c4];
      mword |= (m.x != 0 ? 1u : 0u) << (4 * c4);
      mword |= (m.y != 0 ? 1u : 0u) << (4 * c4 + 1);
      mword |= (m.z != 0 ? 1u : 0u) << (4 * c4 + 2);
      mword |= (m.w != 0 ? 1u : 0u) << (4 * c4 + 3);
    }
  }
  __syncthreads();   // barrier #1

  f32x16 acc[4] = {};     // pooled^T accumulator: tile t -> n = 32t + rl, lane = row
  const int dbase = q * 16;

  for (int dd = 0; dd < 16; ++dd) {
    const int d = dbase + dd;
    const f16_t* base = ws + (size_t)d * PERD_STRIDE;
    // coalesced fragment loads: lane*16B within each 1KB chunk
    f16x8 wf2[2][4];
    #pragma unroll
    for (int t = 0; t < 2; ++t)
      #pragma unroll
      for (int ks = 0; ks < 4; ++ks)
        wf2[t][ks] = *reinterpret_cast<const f16x8*>(base + (t * 4 + ks) * 512 + lane16);

    // ---- h1 fragments in packed f16: h1[l31][16ks+8lh+j] ----
    float xv = x_lds[p * 32 + l31][d];
    f16_t xh = (f16_t)xv;
    f16x8 xv8 = {xh, xh, xh, xh, xh, xh, xh, xh};
    f16x8 h1f[4];
    const f16_t* w1p = base + 12288 + lh * 8;
    const f16_t* b1p = base + 12352 + lh * 8;
    #pragma unroll
    for (int ks = 0; ks < 4; ++ks) {
      f16x8 w1 = *reinterpret_cast<const f16x8*>(w1p + ks * 16);
      f16x8 bb = *reinterpret_cast<const f16x8*>(b1p + ks * 16);
      f16x8 h = xv8 * w1 + bb;
      h1f[ks] = __builtin_elementwise_max(h, (f16x8)(f16_t)0);
    }

    // ---- GEMM1 (swapped): h2^T = W2T x h1^T, acc init = b2 ----
    f32x16 hacc[2];
    #pragma unroll
    for (int t = 0; t < 2; ++t)
      #pragma unroll
      for (int a = 0; a < 4; ++a) {
        float4 bv = *reinterpret_cast<const float4*>(&b2_lds[d][t * 32 + a * 8 + lh * 4]);
        hacc[t][4 * a + 0] = bv.x; hacc[t][4 * a + 1] = bv.y;
        hacc[t][4 * a + 2] = bv.z; hacc[t][4 * a + 3] = bv.w;
      }
    #pragma unroll
    for (int ks = 0; ks < 4; ++ks) {
      hacc[0] = __builtin_amdgcn_mfma_f32_32x32x16_f16(wf2[0][ks], h1f[ks], hacc[0], 0, 0, 0);
      hacc[1] = __builtin_amdgcn_mfma_f32_32x32x16_f16(wf2[1][ks], h1f[ks], hacc[1], 0, 0, 0);
    }
    // relu + mask (lane = data row for C cols)
    const bool mb = (mword >> d) & 1u;
    #pragma unroll
    for (int t = 0; t < 2; ++t)
      #pragma unroll
      for (int r = 0; r < 16; ++r) {
        float v = fmaxf(hacc[t][r], 0.f);
        hacc[t][r] = mb ? v : 0.f;
      }
    // LDS-based in-wave transpose -> GEMM2 B fragments
    f16x8 pf[4];
    xpose2(hacc[0], xrow0, lh, pf[0], pf[1]);
    xpose2(hacc[1], xrow1, lh, pf[2], pf[3]);

    // ---- GEMM2 (swapped): pooled^T += W3T x (m*h2)^T  (acc across d) ----
    const f16_t* w3f = base + 4096;
    #pragma unroll
    for (int t = 0; t < 4; ++t)
      #pragma unroll
      for (int ks = 0; ks < 4; ++ks) {
        f16x8 wf = *reinterpret_cast<const f16x8*>(w3f + (t * 4 + ks) * 512 + lane16);
        acc[t] = __builtin_amdgcn_mfma_f32_32x32x16_f16(wf, pf[ks], acc[t], 0, 0, 0);
      }
  }

  // ---- pool combine across the wave pair ----
  if (q == 1) {
    #pragma unroll
    for (int t = 0; t < 4; ++t)
      #pragma unroll
      for (int a = 0; a < 4; ++a) {
        float4 f = {acc[t][4 * a], acc[t][4 * a + 1], acc[t][4 * a + 2], acc[t][4 * a + 3]};
        *reinterpret_cast<float4*>(&pool_lds[p][lh][l31][(t * 4 + a) * 4]) = f;
      }
  }
  __syncthreads();   // barrier #2
  if (q == 1) return;

  #pragma unroll
  for (int t = 0; t < 4; ++t)
    #pragma unroll
    for (int a = 0; a < 4; ++a) {
      float4 f = *reinterpret_cast<const float4*>(&pool_lds[p][lh][l31][(t * 4 + a) * 4]);
      acc[t][4 * a + 0] += f.x; acc[t][4 * a + 1] += f.y;
      acc[t][4 * a + 2] += f.z; acc[t][4 * a + 3] += f.w;
    }

  // ---- pooled += maskT @ b3 (bias of masked sum), 8 MFMA ----
  {
    f16x8 mf[2];
    #pragma unroll
    for (int ks = 0; ks < 2; ++ks) {
      unsigned w[4];
      #pragma unroll
      for (int i = 0; i < 4; ++i) {
        int d0 = ks * 16 + lh * 8 + 2 * i;
        w[i] = (((mword >> d0) & 1u) ? 0x3C00u : 0u) |
               (((mword >> (d0 + 1)) & 1u) ? 0x3C000000u : 0u);
      }
      uintx4 ww = {w[0], w[1], w[2], w[3]};
      mf[ks] = __builtin_bit_cast(f16x8, ww);
    }
    const f16_t* b3f = ws + B3F_OFF;
    #pragma unroll
    for (int t = 0; t < 4; ++t)
      #pragma unroll
      for (int ks = 0; ks < 2; ++ks) {
        f16x8 bf = *reinterpret_cast<const f16x8*>(b3f + (t * 2 + ks) * 512 + lane16);
        acc[t] = __builtin_amdgcn_mfma_f32_32x32x16_f16(bf, mf[ks], acc[t], 0, 0, 0);
      }
  }

  // ---- R1 (swapped): r1^T = rW1T x pooled^T, K=128 ----
  f16x8 poolf[8];
  xpose2(acc[0], xrow0, lh, poolf[0], poolf[1]);
  xpose2(acc[1], xrow1, lh, poolf[2], poolf[3]);
  xpose2(acc[2], xrow0, lh, poolf[4], poolf[5]);
  xpose2(acc[3], xrow1, lh, poolf[6], poolf[7]);
  f32x16 r1[2];
  #pragma unroll
  for (int t = 0; t < 2; ++t)
    #pragma unroll
    for (int a = 0; a < 4; ++a) {
      float4 bv = *reinterpret_cast<const float4*>(&rb_lds[t * 32 + a * 8 + lh * 4]);
      r1[t][4 * a + 0] = bv.x; r1[t][4 * a + 1] = bv.y;
      r1[t][4 * a + 2] = bv.z; r1[t][4 * a + 3] = bv.w;
    }
  {
    const f16_t* rw1 = ws + RW1F_OFF;
    #pragma unroll
    for (int t = 0; t < 2; ++t)
      #pragma unroll
      for (int ks = 0; ks < 8; ++ks) {
        f16x8 wf = *reinterpret_cast<const f16x8*>(rw1 + (t * 8 + ks) * 512 + lane16);
        r1[t] = __builtin_amdgcn_mfma_f32_32x32x16_f16(wf, poolf[ks], r1[t], 0, 0, 0);
      }
  }
  #pragma unroll
  for (int t = 0; t < 2; ++t)
    #pragma unroll
    for (int r = 0; r < 16; ++r) r1[t][r] = fmaxf(r1[t][r], 0.f);

  // ---- R2 (swapped): r2^T = rW2T x r1^T, K=64 ----
  f16x8 r1f[4];
  xpose2(r1[0], xrow0, lh, r1f[0], r1f[1]);
  xpose2(r1[1], xrow1, lh, r1f[2], r1f[3]);
  f32x16 r2[2];
  #pragma unroll
  for (int t = 0; t < 2; ++t)
    #pragma unroll
    for (int a = 0; a < 4; ++a) {
      float4 bv = *reinterpret_cast<const float4*>(&rb_lds[64 + t * 32 + a * 8 + lh * 4]);
      r2[t][4 * a + 0] = bv.x; r2[t][4 * a + 1] = bv.y;
      r2[t][4 * a + 2] = bv.z; r2[t][4 * a + 3] = bv.w;
    }
  {
    const f16_t* rw2 = ws + RW2F_OFF;
    #pragma unroll
    for (int t = 0; t < 2; ++t)
      #pragma unroll
      for (int ks = 0; ks < 4; ++ks) {
        f16x8 wf = *reinterpret_cast<const f16x8*>(rw2 + (t * 4 + ks) * 512 + lane16);
        r2[t] = __builtin_amdgcn_mfma_f32_32x32x16_f16(wf, r1f[ks], r2[t], 0, 0, 0);
      }
  }
  #pragma unroll
  for (int t = 0; t < 2; ++t)
    #pragma unroll
    for (int r = 0; r < 16; ++r) r2[t][r] = fmaxf(r2[t][r], 0.f);

  // ---- R3 (NON-swapped for coalesced stores): o = r2 @ rW3, N=128 ----
  f16x8 r2f[4];
  xpose2(r2[0], xrow0, lh, r2f[0], r2f[1]);
  xpose2(r2[1], xrow1, lh, r2f[2], r2f[3]);
  f32x16 oacc[4] = {};
  {
    const f16_t* rw3 = ws + RW3F_OFF;
    #pragma unroll
    for (int nt = 0; nt < 4; ++nt)
      #pragma unroll
      for (int ks = 0; ks < 4; ++ks) {
        f16x8 wf = *reinterpret_cast<const f16x8*>(rw3 + (nt * 4 + ks) * 512 + lane16);
        oacc[nt] = __builtin_amdgcn_mfma_f32_32x32x16_f16(r2f[ks], wf, oacc[nt], 0, 0, 0);
      }
  }
  const int rowb = row0 + p * 32;
  #pragma unroll
  for (int nt = 0; nt < 4; ++nt) {
    float rbv = rb_lds[128 + nt * 32 + l31];
    #pragma unroll
    for (int r = 0; r < 16; ++r) {
      int rl = (r & 3) + 8 * (r >> 2) + 4 * lh;
      size_t grow = (size_t)(rowb + rl);
      float v = oacc[nt][r] + rbv;
      if (nt < 2) {
        out[grow * 64 + nt * 32 + l31] = v;
      } else {
        float sp = fmaxf(v, 0.f) + __logf(1.f + __expf(-fabsf(v)));
        out[(size_t)SIG_OFF + grow * 64 + (nt - 2) * 32 + l31] = sp;
      }
    }
  }
}

extern "C" void kernel_launch(void* const* d_in, const int* in_sizes, int n_in,
                              void* d_out, int out_size, void* d_ws, size_t ws_size,
                              hipStream_t stream) {
  const float* x    = (const float*)d_in[0];
  const int*   mask = (const int*)d_in[1];
  const float* W1   = (const float*)d_in[2];
  const float* b1   = (const float*)d_in[3];
  const float* W2   = (const float*)d_in[4];
  const float* b2   = (const float*)d_in[5];
  const float* W3   = (const float*)d_in[6];
  const float* b3   = (const float*)d_in[7];
  const float* rW1  = (const float*)d_in[8];
  const float* rb1  = (const float*)d_in[9];
  const float* rW2  = (const float*)d_in[10];
  const float* rb2  = (const float*)d_in[11];
  const float* rW3  = (const float*)d_in[12];
  const float* rb3  = (const float*)d_in[13];
  float* out = (float*)d_out;
  f16_t* ws = (f16_t*)d_ws;

  convert_weights<<<256, 256, 0, stream>>>(W1, b1, W2, W3, b3, rW1, rW2, rW3, ws);
  indexnet_main<<<NROWS / 64, 256, 0, stream>>>(
      x, mask, b2, rb1, rb2, rb3, ws, out);
}

// Round 6
// 61.090 us; speedup vs baseline: 2.5785x; 1.0472x over previous
//
#include <hip/hip_runtime.h>
#include <hip/hip_bf16.h>
#include <math.h>

typedef _Float16 f16_t;
typedef _Float16 f16x8 __attribute__((ext_vector_type(8)));
typedef float f32x16 __attribute__((ext_vector_type(16)));
typedef unsigned int uintx4 __attribute__((ext_vector_type(4)));
typedef unsigned int uintx2 __attribute__((ext_vector_type(2)));

#define NROWS 32768
#define DD 32
#define SIG_OFF (NROWS * 64)

// ---------------- ws layout (f16 elements) ----------------
// All GEMM weights are stored in PER-WAVE FRAGMENT-LOAD ORDER:
//   [tile][ks][lane(0..63)][j(0..7)]  -> each fragment load is lane*16B,
// fully coalesced. Fragment element semantics: lane = l31 + 32*lh;
//   n = tile*32 + l31; k = ks*16 + lh*8 + j.
#define PERD_STRIDE 12416          // per-d super-block: wf2 4096 | wf3 8192 | w1 64 | b1 64
#define RW1F_OFF   397312          // 2t x 8ks x 512 = 8192   (rW1[k][n], k<128)
#define RW2F_OFF   405504          // 2t x 4ks x 512 = 4096   (rW2[k][n], k<64)
#define RW3F_OFF   409600          // 4nt x 4ks x 512 = 8192  (rW3[k][n], n<128)
#define B3F_OFF    417792          // 4t x 2ks x 512 = 4096   (b3[d][n] as B-frag, "k"=d)
#define WS_ELEMS   421888

__global__ void convert_weights(const float* __restrict__ W1,
                                const float* __restrict__ b1,
                                const float* __restrict__ W2,
                                const float* __restrict__ W3,
                                const float* __restrict__ b3,
                                const float* __restrict__ rW1,
                                const float* __restrict__ rW2,
                                const float* __restrict__ rW3,
                                f16_t* __restrict__ ws) {
  for (int i = blockIdx.x * blockDim.x + threadIdx.x; i < WS_ELEMS;
       i += gridDim.x * blockDim.x) {
    float v;
    if (i < RW1F_OFF) {
      int d = i / PERD_STRIDE;
      int r = i - d * PERD_STRIDE;
      if (r < 4096) {                 // wf2 fragments: W2[d][k][n], n<64
        int t = r >> 11, ks = (r >> 9) & 3, lane = (r >> 3) & 63, j = r & 7;
        int n = t * 32 + (lane & 31);
        int k = ks * 16 + (lane >> 5) * 8 + j;
        v = W2[(d * 64 + k) * 64 + n];
      } else if (r < 12288) {         // wf3 fragments: W3[d][k][n], n<128
        int r2 = r - 4096;
        int t = r2 >> 11, ks = (r2 >> 9) & 3, lane = (r2 >> 3) & 63, j = r2 & 7;
        int n = t * 32 + (lane & 31);
        int k = ks * 16 + (lane >> 5) * 8 + j;
        v = W3[(d * 64 + k) * 128 + n];
      } else if (r < 12352) {         // w1 (linear, broadcast-read)
        v = W1[d * 64 + (r - 12288)];
      } else {                        // b1 (linear)
        v = b1[d * 64 + (r - 12352)];
      }
    } else if (i < RW2F_OFF) {        // rW1 fragments, k<128
      int i2 = i - RW1F_OFF;
      int t = i2 >> 12, ks = (i2 >> 9) & 7, lane = (i2 >> 3) & 63, j = i2 & 7;
      int n = t * 32 + (lane & 31);
      int k = ks * 16 + (lane >> 5) * 8 + j;
      v = rW1[k * 64 + n];
    } else if (i < RW3F_OFF) {        // rW2 fragments, k<64
      int i2 = i - RW2F_OFF;
      int t = i2 >> 11, ks = (i2 >> 9) & 3, lane = (i2 >> 3) & 63, j = i2 & 7;
      int n = t * 32 + (lane & 31);
      int k = ks * 16 + (lane >> 5) * 8 + j;
      v = rW2[k * 64 + n];
    } else if (i < B3F_OFF) {         // rW3 fragments, output col n<128, k<64
      int i2 = i - RW3F_OFF;
      int nt = i2 >> 11, ks = (i2 >> 9) & 3, lane = (i2 >> 3) & 63, j = i2 & 7;
      int n = nt * 32 + (lane & 31);
      int k = ks * 16 + (lane >> 5) * 8 + j;
      v = rW3[k * 128 + n];
    } else {                          // b3 as B-fragment: "k" axis = d (32)
      int i2 = i - B3F_OFF;
      int t = i2 >> 10, ks = (i2 >> 9) & 1, lane = (i2 >> 3) & 63, j = i2 & 7;
      int n = t * 32 + (lane & 31);
      int dsrc = ks * 16 + (lane >> 5) * 8 + j;
      v = b3[dsrc * 128 + n];
    }
    ws[i] = (f16_t)v;
  }
}

// Transpose a swapped-GEMM C tile (lane = data-row l31, regs = 16 n-values:
// n = (reg&3)+8*(reg>>2)+4*lh) into two B fragments (lane supplies
// n = 16*kk + 8*lh + j, j=0..7 contiguous) via a PER-WAVE private LDS
// round-trip. Within-wave ds_write->ds_read ordering is a compiler-visible
// LDS dependence (lgkmcnt inserted automatically) -- no barrier needed.
__device__ __forceinline__ void xpose2(const f32x16& c, unsigned* row, int lh,
                                       f16x8& o0, f16x8& o1) {
  #pragma unroll
  for (int a = 0; a < 4; ++a) {
    uintx2 w;
    w.x = __builtin_bit_cast(unsigned, __builtin_amdgcn_cvt_pkrtz(c[4 * a + 0], c[4 * a + 1]));
    w.y = __builtin_bit_cast(unsigned, __builtin_amdgcn_cvt_pkrtz(c[4 * a + 2], c[4 * a + 3]));
    *reinterpret_cast<uintx2*>(row + 4 * a + 2 * lh) = w;
  }
  uintx2 ra = *reinterpret_cast<const uintx2*>(row + 4 * lh);
  uintx2 rb = *reinterpret_cast<const uintx2*>(row + 4 * lh + 2);
  uintx2 rc = *reinterpret_cast<const uintx2*>(row + 8 + 4 * lh);
  uintx2 rd = *reinterpret_cast<const uintx2*>(row + 8 + 4 * lh + 2);
  uintx4 w0 = {ra.x, ra.y, rb.x, rb.y};
  uintx4 w1 = {rc.x, rc.y, rd.x, rd.y};
  o0 = __builtin_bit_cast(f16x8, w0);
  o1 = __builtin_bit_cast(f16x8, w1);
}

// Block = 256 thr = 4 waves = 2 pairs. Pair p owns rows blk*64+p*32+(lane&31).
// Wave parity q: d-range [q*16, q*16+16). All layer GEMMs are computed
// swapped (C' = W^T x act^T) so activations stay lane-local; transposes via
// per-wave LDS round-trip (xpose2). Pool accumulates inside the GEMM2 MFMA
// accumulator across d (mask folded into h2). Barriers: 2 total.
// Round 6: all 24 weight-fragment loads batched at body top (one vmcnt
// batch/iter instead of ~8 serialized ones); x held in registers.
__launch_bounds__(256, 2)
__global__ void indexnet_main(const float* __restrict__ x,
                              const int* __restrict__ mask,
                              const float* __restrict__ b2,
                              const float* __restrict__ rb1,
                              const float* __restrict__ rb2,
                              const float* __restrict__ rb3,
                              const f16_t* __restrict__ ws,
                              float* __restrict__ out) {
  __shared__ float b2_lds[32][64];
  __shared__ float rb_lds[256];                        // rb1 | rb2 | rb3
  __shared__ float pool_lds[2][2][32][68];             // [pair][lh][l31][64+pad]
  __shared__ __align__(16) unsigned xp_lds[4][2][32][18];  // per-wave xpose scratch

  const int tid = threadIdx.x;
  const int lane = tid & 63;
  const int wid = tid >> 6;
  const int p = wid >> 1;          // pair (row group)
  const int q = wid & 1;           // d-range half
  const int l31 = lane & 31;
  const int lh = lane >> 5;
  const int row0 = blockIdx.x * 64;
  const int lane16 = lane * 8;     // f16 offset of this lane's 16B fragment chunk

  unsigned* xrow0 = &xp_lds[wid][0][l31][0];
  unsigned* xrow1 = &xp_lds[wid][1][l31][0];

  // ---- stage b2 [32][64] (flat copy) ----
  {
    float4* dst = reinterpret_cast<float4*>(&b2_lds[0][0]);
    const float4* src = reinterpret_cast<const float4*>(b2);
    dst[tid * 2] = src[tid * 2];
    dst[tid * 2 + 1] = src[tid * 2 + 1];
  }
  // ---- stage readout biases ----
  if (tid < 64)       rb_lds[tid] = rb1[tid];
  else if (tid < 128) rb_lds[tid] = rb2[tid - 64];
  else                rb_lds[tid] = rb3[tid - 128];

  // ---- per-lane mask word for own row ----
  unsigned mword = 0;
  {
    const int4* mrow = reinterpret_cast<const int4*>(mask + (size_t)(row0 + p * 32 + l31) * DD);
    #pragma unroll
    for (int c4 = 0; c4 < 8; ++c4) {
      int4 m = mrow[c4];
      mword |= (m.x != 0 ? 1u : 0u) << (4 * c4);
      mword |= (m.y != 0 ? 1u : 0u) << (4 * c4 + 1);
      mword |= (m.z != 0 ? 1u : 0u) << (4 * c4 + 2);
      mword |= (m.w != 0 ? 1u : 0u) << (4 * c4 + 3);
    }
  }
  // ---- per-lane x row (own 16 d's) stays in global; loaded per 4-group ----
  const float* xrow = x + (size_t)(row0 + p * 32 + l31) * DD + q * 16;

  __syncthreads();   // barrier #1 (b2_lds, rb_lds ready)

  f32x16 acc[4] = {};     // pooled^T accumulator: tile t -> n = 32t + rl, lane = row
  const int dbase = q * 16;

  for (int dd0 = 0; dd0 < 16; dd0 += 4) {
    // 4 d-values of x for this group (one coalesced-ish float4, 8 per kernel)
    float4 xv4 = *reinterpret_cast<const float4*>(xrow + dd0);
    #pragma unroll
    for (int j = 0; j < 4; ++j) {
      const int d = dbase + dd0 + j;
      const f16_t* base = ws + (size_t)d * PERD_STRIDE;

      // ---- batched weight-fragment loads: 24 coalesced 16B/lane loads ----
      f16x8 wf2[2][4], wf3[4][4];
      #pragma unroll
      for (int t = 0; t < 2; ++t)
        #pragma unroll
        for (int ks = 0; ks < 4; ++ks)
          wf2[t][ks] = *reinterpret_cast<const f16x8*>(base + (t * 4 + ks) * 512 + lane16);
      #pragma unroll
      for (int t = 0; t < 4; ++t)
        #pragma unroll
        for (int ks = 0; ks < 4; ++ks)
          wf3[t][ks] = *reinterpret_cast<const f16x8*>(base + 4096 + (t * 4 + ks) * 512 + lane16);

      // ---- h1 fragments in packed f16: h1[l31][16ks+8lh+j] ----
      float xv = (j == 0) ? xv4.x : (j == 1) ? xv4.y : (j == 2) ? xv4.z : xv4.w;
      f16_t xh = (f16_t)xv;
      f16x8 xv8 = {xh, xh, xh, xh, xh, xh, xh, xh};
      f16x8 h1f[4];
      const f16_t* w1p = base + 12288 + lh * 8;
      const f16_t* b1p = base + 12352 + lh * 8;
      #pragma unroll
      for (int ks = 0; ks < 4; ++ks) {
        f16x8 w1 = *reinterpret_cast<const f16x8*>(w1p + ks * 16);
        f16x8 bb = *reinterpret_cast<const f16x8*>(b1p + ks * 16);
        f16x8 h = xv8 * w1 + bb;
        h1f[ks] = __builtin_elementwise_max(h, (f16x8)(f16_t)0);
      }

      // ---- GEMM1 (swapped): h2^T = W2T x h1^T, acc init = b2 ----
      f32x16 hacc[2];
      #pragma unroll
      for (int t = 0; t < 2; ++t)
        #pragma unroll
        for (int a = 0; a < 4; ++a) {
          float4 bv = *reinterpret_cast<const float4*>(&b2_lds[d][t * 32 + a * 8 + lh * 4]);
          hacc[t][4 * a + 0] = bv.x; hacc[t][4 * a + 1] = bv.y;
          hacc[t][4 * a + 2] = bv.z; hacc[t][4 * a + 3] = bv.w;
        }
      #pragma unroll
      for (int ks = 0; ks < 4; ++ks) {
        hacc[0] = __builtin_amdgcn_mfma_f32_32x32x16_f16(wf2[0][ks], h1f[ks], hacc[0], 0, 0, 0);
        hacc[1] = __builtin_amdgcn_mfma_f32_32x32x16_f16(wf2[1][ks], h1f[ks], hacc[1], 0, 0, 0);
      }
      // relu + mask (lane = data row for C cols)
      const bool mb = (mword >> d) & 1u;
      #pragma unroll
      for (int t = 0; t < 2; ++t)
        #pragma unroll
        for (int r = 0; r < 16; ++r) {
          float v = fmaxf(hacc[t][r], 0.f);
          hacc[t][r] = mb ? v : 0.f;
        }
      // LDS-based in-wave transpose -> GEMM2 B fragments
      f16x8 pf[4];
      xpose2(hacc[0], xrow0, lh, pf[0], pf[1]);
      xpose2(hacc[1], xrow1, lh, pf[2], pf[3]);

      // ---- GEMM2 (swapped): pooled^T += W3T x (m*h2)^T  (acc across d) ----
      #pragma unroll
      for (int t = 0; t < 4; ++t)
        #pragma unroll
        for (int ks = 0; ks < 4; ++ks)
          acc[t] = __builtin_amdgcn_mfma_f32_32x32x16_f16(wf3[t][ks], pf[ks], acc[t], 0, 0, 0);
    }
  }

  // ---- pool combine across the wave pair ----
  if (q == 1) {
    #pragma unroll
    for (int t = 0; t < 4; ++t)
      #pragma unroll
      for (int a = 0; a < 4; ++a) {
        float4 f = {acc[t][4 * a], acc[t][4 * a + 1], acc[t][4 * a + 2], acc[t][4 * a + 3]};
        *reinterpret_cast<float4*>(&pool_lds[p][lh][l31][(t * 4 + a) * 4]) = f;
      }
  }
  __syncthreads();   // barrier #2
  if (q == 1) return;

  #pragma unroll
  for (int t = 0; t < 4; ++t)
    #pragma unroll
    for (int a = 0; a < 4; ++a) {
      float4 f = *reinterpret_cast<const float4*>(&pool_lds[p][lh][l31][(t * 4 + a) * 4]);
      acc[t][4 * a + 0] += f.x; acc[t][4 * a + 1] += f.y;
      acc[t][4 * a + 2] += f.z; acc[t][4 * a + 3] += f.w;
    }

  // ---- pooled += maskT @ b3 (bias of masked sum), 8 MFMA ----
  {
    f16x8 mf[2];
    #pragma unroll
    for (int ks = 0; ks < 2; ++ks) {
      unsigned w[4];
      #pragma unroll
      for (int i = 0; i < 4; ++i) {
        int d0 = ks * 16 + lh * 8 + 2 * i;
        w[i] = (((mword >> d0) & 1u) ? 0x3C00u : 0u) |
               (((mword >> (d0 + 1)) & 1u) ? 0x3C000000u : 0u);
      }
      uintx4 ww = {w[0], w[1], w[2], w[3]};
      mf[ks] = __builtin_bit_cast(f16x8, ww);
    }
    const f16_t* b3f = ws + B3F_OFF;
    #pragma unroll
    for (int t = 0; t < 4; ++t)
      #pragma unroll
      for (int ks = 0; ks < 2; ++ks) {
        f16x8 bf = *reinterpret_cast<const f16x8*>(b3f + (t * 2 + ks) * 512 + lane16);
        acc[t] = __builtin_amdgcn_mfma_f32_32x32x16_f16(bf, mf[ks], acc[t], 0, 0, 0);
      }
  }

  // ---- R1 (swapped): r1^T = rW1T x pooled^T, K=128 ----
  f16x8 poolf[8];
  xpose2(acc[0], xrow0, lh, poolf[0], poolf[1]);
  xpose2(acc[1], xrow1, lh, poolf[2], poolf[3]);
  xpose2(acc[2], xrow0, lh, poolf[4], poolf[5]);
  xpose2(acc[3], xrow1, lh, poolf[6], poolf[7]);
  f32x16 r1[2];
  #pragma unroll
  for (int t = 0; t < 2; ++t)
    #pragma unroll
    for (int a = 0; a < 4; ++a) {
      float4 bv = *reinterpret_cast<const float4*>(&rb_lds[t * 32 + a * 8 + lh * 4]);
      r1[t][4 * a + 0] = bv.x; r1[t][4 * a + 1] = bv.y;
      r1[t][4 * a + 2] = bv.z; r1[t][4 * a + 3] = bv.w;
    }
  {
    const f16_t* rw1 = ws + RW1F_OFF;
    #pragma unroll
    for (int t = 0; t < 2; ++t)
      #pragma unroll
      for (int ks = 0; ks < 8; ++ks) {
        f16x8 wf = *reinterpret_cast<const f16x8*>(rw1 + (t * 8 + ks) * 512 + lane16);
        r1[t] = __builtin_amdgcn_mfma_f32_32x32x16_f16(wf, poolf[ks], r1[t], 0, 0, 0);
      }
  }
  #pragma unroll
  for (int t = 0; t < 2; ++t)
    #pragma unroll
    for (int r = 0; r < 16; ++r) r1[t][r] = fmaxf(r1[t][r], 0.f);

  // ---- R2 (swapped): r2^T = rW2T x r1^T, K=64 ----
  f16x8 r1f[4];
  xpose2(r1[0], xrow0, lh, r1f[0], r1f[1]);
  xpose2(r1[1], xrow1, lh, r1f[2], r1f[3]);
  f32x16 r2[2];
  #pragma unroll
  for (int t = 0; t < 2; ++t)
    #pragma unroll
    for (int a = 0; a < 4; ++a) {
      float4 bv = *reinterpret_cast<const float4*>(&rb_lds[64 + t * 32 + a * 8 + lh * 4]);
      r2[t][4 * a + 0] = bv.x; r2[t][4 * a + 1] = bv.y;
      r2[t][4 * a + 2] = bv.z; r2[t][4 * a + 3] = bv.w;
    }
  {
    const f16_t* rw2 = ws + RW2F_OFF;
    #pragma unroll
    for (int t = 0; t < 2; ++t)
      #pragma unroll
      for (int ks = 0; ks < 4; ++ks) {
        f16x8 wf = *reinterpret_cast<const f16x8*>(rw2 + (t * 4 + ks) * 512 + lane16);
        r2[t] = __builtin_amdgcn_mfma_f32_32x32x16_f16(wf, r1f[ks], r2[t], 0, 0, 0);
      }
  }
  #pragma unroll
  for (int t = 0; t < 2; ++t)
    #pragma unroll
    for (int r = 0; r < 16; ++r) r2[t][r] = fmaxf(r2[t][r], 0.f);

  // ---- R3 (NON-swapped for coalesced stores): o = r2 @ rW3, N=128 ----
  f16x8 r2f[4];
  xpose2(r2[0], xrow0, lh, r2f[0], r2f[1]);
  xpose2(r2[1], xrow1, lh, r2f[2], r2f[3]);
  f32x16 oacc[4] = {};
  {
    const f16_t* rw3 = ws + RW3F_OFF;
    #pragma unroll
    for (int nt = 0; nt < 4; ++nt)
      #pragma unroll
      for (int ks = 0; ks < 4; ++ks) {
        f16x8 wf = *reinterpret_cast<const f16x8*>(rw3 + (nt * 4 + ks) * 512 + lane16);
        oacc[nt] = __builtin_amdgcn_mfma_f32_32x32x16_f16(r2f[ks], wf, oacc[nt], 0, 0, 0);
      }
  }
  const int rowb = row0 + p * 32;
  #pragma unroll
  for (int nt = 0; nt < 4; ++nt) {
    float rbv = rb_lds[128 + nt * 32 + l31];
    #pragma unroll
    for (int r = 0; r < 16; ++r) {
      int rl = (r & 3) + 8 * (r >> 2) + 4 * lh;
      size_t grow = (size_t)(rowb + rl);
      float v = oacc[nt][r] + rbv;
      if (nt < 2) {
        out[grow * 64 + nt * 32 + l31] = v;
      } else {
        float sp = fmaxf(v, 0.f) + __logf(1.f + __expf(-fabsf(v)));
        out[(size_t)SIG_OFF + grow * 64 + (nt - 2) * 32 + l31] = sp;
      }
    }
  }
}

extern "C" void kernel_launch(void* const* d_in, const int* in_sizes, int n_in,
                              void* d_out, int out_size, void* d_ws, size_t ws_size,
                              hipStream_t stream) {
  const float* x    = (const float*)d_in[0];
  const int*   mask = (const int*)d_in[1];
  const float* W1   = (const float*)d_in[2];
  const float* b1   = (const float*)d_in[3];
  const float* W2   = (const float*)d_in[4];
  const float* b2   = (const float*)d_in[5];
  const float* W3   = (const float*)d_in[6];
  const float* b3   = (const float*)d_in[7];
  const float* rW1  = (const float*)d_in[8];
  const float* rb1  = (const float*)d_in[9];
  const float* rW2  = (const float*)d_in[10];
  const float* rb2  = (const float*)d_in[11];
  const float* rW3  = (const float*)d_in[12];
  const float* rb3  = (const float*)d_in[13];
  float* out = (float*)d_out;
  f16_t* ws = (f16_t*)d_ws;

  convert_weights<<<256, 256, 0, stream>>>(W1, b1, W2, W3, b3, rW1, rW2, rW3, ws);
  indexnet_main<<<NROWS / 64, 256, 0, stream>>>(
      x, mask, b2, rb1, rb2, rb3, ws, out);
}